// Round 1
// baseline (1756.708 us; speedup 1.0000x reference)
//
#include <hip/hip_runtime.h>
#include <hip/hip_bf16.h>
#include <math.h>

#define S_LEN 4096
#define DMODEL 768
#define NHEADS 12
#define DH 64
#define FDIM 3072
#define NEXP 7
#define NPAIR (2*S_LEN)

typedef __bf16 bf16x8 __attribute__((ext_vector_type(8)));
typedef float f32x4 __attribute__((ext_vector_type(4)));

__device__ __forceinline__ unsigned short f2bf(float f){
  union { float f; unsigned u; } v; v.f = f;
  unsigned r = v.u + 0x7fffu + ((v.u >> 16) & 1u);
  return (unsigned short)(r >> 16);
}
__device__ __forceinline__ float bf2f(unsigned short h){
  union { unsigned u; float f; } v; v.u = ((unsigned)h) << 16;
  return v.f;
}
__device__ __forceinline__ float gelu_f(float x){
  return 0.5f * x * (1.0f + erff(x * 0.7071067811865475f));
}
__device__ __forceinline__ f32x4 mfma16(bf16x8 a, bf16x8 b, f32x4 c){
  return __builtin_amdgcn_mfma_f32_16x16x32_bf16(a, b, c, 0, 0, 0);
}

// ---------------- elementwise fp32 -> bf16 hi/lo split ----------------
__global__ __launch_bounds__(256) void split_kernel(const float* __restrict__ in,
    unsigned short* __restrict__ hi, unsigned short* __restrict__ lo, int n){
  int i = blockIdx.x*256 + threadIdx.x;
  if (i >= n) return;
  float v = in[i];
  unsigned short h = f2bf(v);
  hi[i] = h;
  lo[i] = f2bf(v - bf2f(h));
}

// ---------------- elementwise fp32 -> bf16 ----------------
__global__ __launch_bounds__(256) void cast_kernel(const float* __restrict__ in,
    unsigned short* __restrict__ out, int n){
  int i = blockIdx.x*256 + threadIdx.x;
  if (i >= n) return;
  out[i] = f2bf(in[i]);
}

// ---------------- tiled transpose + convert: in [mat][R][C] f32 -> out [mat][C][R] bf16 (hi[,lo]) ----------------
template<int SPLIT>
__global__ __launch_bounds__(256) void transp_kernel(const float* __restrict__ in,
    unsigned short* __restrict__ hi, unsigned short* __restrict__ lo,
    int R, int C, long inStride, long outStride){
  const float* ip = in + (long)blockIdx.z * inStride;
  long ob = (long)blockIdx.z * outStride;
  __shared__ float tile[32][33];
  int c0 = blockIdx.x*32, r0 = blockIdx.y*32;
  for (int i = threadIdx.y; i < 32; i += 8)
    tile[i][threadIdx.x] = ip[(long)(r0+i)*C + c0 + threadIdx.x];
  __syncthreads();
  for (int i = threadIdx.y; i < 32; i += 8){
    float v = tile[threadIdx.x][i];
    long oidx = ob + (long)(c0+i)*R + r0 + threadIdx.x;
    unsigned short h = f2bf(v);
    hi[oidx] = h;
    if (SPLIT) lo[oidx] = f2bf(v - bf2f(h));
  }
}

// ---------------- generic 128x128x32 bf16 MFMA GEMM, B^T ("Bt[n][k]") layout ----------------
// MODE: 0=QKV  1=WO  2=MOE1(gather)  3=MOE2(scatter+atomic)  4=WD
struct GemmP {
  const unsigned short* A;
  const unsigned short* Alo;
  const unsigned short* B;
  const unsigned short* Blo;
  int M, N, K;
  const float* bias;  const float* bias2; const float* bias3;
  const float* resid;
  float* outF;
  unsigned short* outBF;
  float* outQ; float* outK; float* outV;
  const int* pair_token;
  const float* pair_w;
  const int* cnt;
  const int* offs;
};

template<int MODE, int PLANES>
__global__ __launch_bounds__(256, 2) void gemm_bt(GemmP p){
  const int tid  = threadIdx.x;
  const int lane = tid & 63;
  const int wave = tid >> 6;
  const int quad = lane >> 4;
  const int ln   = lane & 15;
  const int wr = wave >> 1, wc = wave & 1;
  const int bn0 = blockIdx.x * 128;
  const int bm0 = blockIdx.y * 128;
  const int K = p.K;

  int e = 0, eoff = 0, Mloc = p.M;
  if (MODE == 2 || MODE == 3){
    e = blockIdx.z;
    eoff = p.offs[e];
    Mloc = p.cnt[e];
    if (bm0 >= Mloc) return;
  }
  const unsigned short* Bp = p.B + ((MODE == 2 || MODE == 3) ? (long)e * FDIM * DMODEL : 0);

  long aoff[2]; long boff[2];
  #pragma unroll
  for (int j = 0; j < 2; j++){
    int c = tid + j*256;
    int row = c >> 2;
    if (MODE == 2){
      int r = bm0 + row; if (r >= Mloc) r = Mloc - 1;
      aoff[j] = (long)p.pair_token[eoff + r] * K;
    } else if (MODE == 3){
      int r = bm0 + row; if (r >= Mloc) r = Mloc - 1;
      aoff[j] = (long)(eoff + r) * K;
    } else {
      aoff[j] = (long)(bm0 + row) * K;
    }
    boff[j] = (long)(bn0 + row) * K;
  }

  __shared__ __align__(16) unsigned short As[PLANES][128*32];
  __shared__ __align__(16) unsigned short Bs[PLANES][128*32];

  f32x4 zero4 = {0.f, 0.f, 0.f, 0.f};
  f32x4 acc[4][4];
  #pragma unroll
  for (int i = 0; i < 4; i++)
    #pragma unroll
    for (int j = 0; j < 4; j++) acc[i][j] = zero4;

  for (int k0 = 0; k0 < K; k0 += 32){
    uint4 av[2][PLANES], bv[2][PLANES];
    #pragma unroll
    for (int j = 0; j < 2; j++){
      int c = tid + j*256;
      int koff = (c & 3) * 8;
      av[j][0] = *(const uint4*)(p.A + aoff[j] + k0 + koff);
      bv[j][0] = *(const uint4*)(Bp  + boff[j] + k0 + koff);
      if (PLANES == 2){
        av[j][1] = *(const uint4*)(p.Alo + aoff[j] + k0 + koff);
        bv[j][1] = *(const uint4*)(p.Blo + boff[j] + k0 + koff);
      }
    }
    __syncthreads();
    #pragma unroll
    for (int j = 0; j < 2; j++){
      int c = tid + j*256;
      #pragma unroll
      for (int pl = 0; pl < PLANES; pl++){
        ((uint4*)&As[pl][0])[c] = av[j][pl];
        ((uint4*)&Bs[pl][0])[c] = bv[j][pl];
      }
    }
    __syncthreads();
    bf16x8 af[PLANES][4], bfr[PLANES][4];
    #pragma unroll
    for (int mt = 0; mt < 4; mt++)
      #pragma unroll
      for (int pl = 0; pl < PLANES; pl++)
        af[pl][mt] = *(const bf16x8*)&As[pl][(wr*64 + mt*16 + ln)*32 + quad*8];
    #pragma unroll
    for (int nt = 0; nt < 4; nt++)
      #pragma unroll
      for (int pl = 0; pl < PLANES; pl++)
        bfr[pl][nt] = *(const bf16x8*)&Bs[pl][(wc*64 + nt*16 + ln)*32 + quad*8];
    #pragma unroll
    for (int mt = 0; mt < 4; mt++){
      #pragma unroll
      for (int nt = 0; nt < 4; nt++){
        acc[mt][nt] = mfma16(af[0][mt], bfr[0][nt], acc[mt][nt]);
        if (PLANES == 2){
          acc[mt][nt] = mfma16(af[0][mt], bfr[1][nt], acc[mt][nt]);
          acc[mt][nt] = mfma16(af[1][mt], bfr[0][nt], acc[mt][nt]);
        }
      }
    }
  }

  #pragma unroll
  for (int mt = 0; mt < 4; mt++){
    #pragma unroll
    for (int nt = 0; nt < 4; nt++){
      #pragma unroll
      for (int r = 0; r < 4; r++){
        int gm = bm0 + wr*64 + mt*16 + quad*4 + r;
        int gn = bn0 + wc*64 + nt*16 + ln;
        float v = acc[mt][nt][r];
        if (MODE == 0){
          int which = gn >= 1536 ? 2 : (gn >= 768 ? 1 : 0);
          int nn = gn - which*768;
          int hh = nn >> 6, dh = nn & 63;
          float* dst;
          if (which == 0){ v = (v + p.bias[nn]) * 0.125f; dst = p.outQ; }
          else if (which == 1){ v = v + p.bias2[nn]; dst = p.outK; }
          else { v = v + p.bias3[nn]; dst = p.outV; }
          dst[((long)hh*S_LEN + gm)*64 + dh] = v;
        } else if (MODE == 1 || MODE == 4){
          long i = (long)gm*DMODEL + gn;
          p.outF[i] = v + p.bias[gn] + p.resid[i];
        } else if (MODE == 2){
          if (gm < Mloc){
            v = gelu_f(v + p.bias[(long)e*FDIM + gn]);
            p.outBF[(long)(eoff + gm)*FDIM + gn] = f2bf(v);
          }
        } else if (MODE == 3){
          if (gm < Mloc){
            int pi = eoff + gm;
            v = (v + p.bias[(long)e*DMODEL + gn]) * p.pair_w[pi];
            atomicAdd(&p.outF[(long)p.pair_token[pi]*DMODEL + gn], v);
          }
        }
      }
    }
  }
}

// ---------------- fp32 sliding-window attention (flash-style, online softmax) ----------------
// grid (16 chunks, 12 heads, 4 sub-blocks of 64 queries); block 256
__global__ __launch_bounds__(256) void attn_kernel(const float* __restrict__ Qf,
    const float* __restrict__ Kf, const float* __restrict__ Vf,
    unsigned short* __restrict__ attn_hi, unsigned short* __restrict__ attn_lo){
  const int c  = blockIdx.x;
  const int h  = blockIdx.y;
  const int qb = blockIdx.z;
  const int tid = threadIdx.x;
  const int q0abs = c*256 + qb*64;

  __shared__ float Ks[64*64];     // [key][d]
  __shared__ float Vs[64*64];     // [key][d]
  __shared__ float Ps[64*66];     // [q][key] (pad 2)
  __shared__ float alphaA[64];
  __shared__ float lA[64];

  const int qg = tid & 31;        // 2 queries each
  const int kg = tid >> 5;        // 8 keys (S phase) / 8 dims (PV phase)
  const int qa0 = q0abs + qg*2;
  const float* qrow0 = Qf + ((long)h*S_LEN + qa0)*64;
  const float* qrow1 = qrow0 + 64;

  float m_st = -1e30f, l_st = 0.f;   // valid for tid<64 (row threads)
  float O0[8], O1[8];
  #pragma unroll
  for (int j = 0; j < 8; j++){ O0[j] = 0.f; O1[j] = 0.f; }

  for (int kb = 0; kb < 12; kb++){
    const int kstart = c*256 - 256 + kb*64;
    __syncthreads();   // prior-iteration readers of Ks/Vs/Ps done
    for (int i = tid; i < 64*64; i += 256){
      int key = i >> 6;
      int ka = kstart + key;
      int kac = ka < 0 ? 0 : (ka >= S_LEN ? S_LEN-1 : ka);
      long gi = ((long)h*S_LEN + kac)*64 + (i & 63);
      Ks[i] = Kf[gi];
      Vs[i] = Vf[gi];
    }
    __syncthreads();
    // ---- scores: 2q x 8k per thread ----
    float s0[8], s1[8];
    #pragma unroll
    for (int j = 0; j < 8; j++){ s0[j] = 0.f; s1[j] = 0.f; }
    #pragma unroll 4
    for (int d4 = 0; d4 < 16; d4++){
      float4 q0 = *(const float4*)(qrow0 + d4*4);
      float4 q1 = *(const float4*)(qrow1 + d4*4);
      #pragma unroll
      for (int j = 0; j < 8; j++){
        float4 k4 = *(const float4*)&Ks[(kg*8+j)*64 + d4*4];
        s0[j] += q0.x*k4.x + q0.y*k4.y + q0.z*k4.z + q0.w*k4.w;
        s1[j] += q1.x*k4.x + q1.y*k4.y + q1.z*k4.z + q1.w*k4.w;
      }
    }
    #pragma unroll
    for (int j = 0; j < 8; j++){
      int ka = kstart + kg*8 + j;
      bool ok = (ka >= 0) && (ka < S_LEN);
      bool v0 = ok && (ka >= qa0-256)   && (ka <= qa0+256);
      bool v1 = ok && (ka >= qa0+1-256) && (ka <= qa0+1+256);
      Ps[(qg*2  )*66 + kg*8 + j] = v0 ? s0[j] : -1e9f;
      Ps[(qg*2+1)*66 + kg*8 + j] = v1 ? s1[j] : -1e9f;
    }
    __syncthreads();
    // ---- online softmax row update (one thread per query) ----
    if (tid < 64){
      float* prow = &Ps[tid*66];
      float bm = -1e30f;
      for (int k = 0; k < 64; k++) bm = fmaxf(bm, prow[k]);
      float mnew = fmaxf(m_st, bm);
      float al = __expf(m_st - mnew);
      float se = 0.f;
      for (int k = 0; k < 64; k++){
        float pv = __expf(prow[k] - mnew);
        prow[k] = pv;
        se += pv;
      }
      l_st = l_st*al + se;
      m_st = mnew;
      alphaA[tid] = al;
    }
    __syncthreads();
    // ---- PV accumulate: 2q x 8d per thread ----
    {
      float a0 = alphaA[qg*2], a1 = alphaA[qg*2+1];
      #pragma unroll
      for (int j = 0; j < 8; j++){ O0[j] *= a0; O1[j] *= a1; }
      const float* p0r = &Ps[(qg*2)*66];
      const float* p1r = p0r + 66;
      for (int k = 0; k < 64; k++){
        float p0 = p0r[k], p1 = p1r[k];
        const float4* vr = (const float4*)&Vs[k*64 + kg*8];
        float4 va = vr[0], vb = vr[1];
        O0[0]+=p0*va.x; O0[1]+=p0*va.y; O0[2]+=p0*va.z; O0[3]+=p0*va.w;
        O0[4]+=p0*vb.x; O0[5]+=p0*vb.y; O0[6]+=p0*vb.z; O0[7]+=p0*vb.w;
        O1[0]+=p1*va.x; O1[1]+=p1*va.y; O1[2]+=p1*va.z; O1[3]+=p1*va.w;
        O1[4]+=p1*vb.x; O1[5]+=p1*vb.y; O1[6]+=p1*vb.z; O1[7]+=p1*vb.w;
      }
    }
  }
  if (tid < 64) lA[tid] = l_st;
  __syncthreads();
  {
    float i0 = 1.f / lA[qg*2], i1 = 1.f / lA[qg*2+1];
    long b0 = (long)qa0*DMODEL + h*64 + kg*8;
    #pragma unroll
    for (int j = 0; j < 8; j++){
      float o0 = O0[j]*i0, o1 = O1[j]*i1;
      unsigned short h0 = f2bf(o0);
      attn_hi[b0 + j] = h0;
      attn_lo[b0 + j] = f2bf(o0 - bf2f(h0));
      unsigned short h1 = f2bf(o1);
      attn_hi[b0 + DMODEL + j] = h1;
      attn_lo[b0 + DMODEL + j] = f2bf(o1 - bf2f(h1));
    }
  }
}

// ---------------- LayerNorm (fp32), optional bf16 copy ----------------
__global__ __launch_bounds__(256) void ln_kernel(const float* __restrict__ x,
    const float* __restrict__ g, const float* __restrict__ b,
    float* __restrict__ outF, unsigned short* __restrict__ outBF){
  int s = blockIdx.x;
  const float* row = x + (long)s*DMODEL;
  int t = threadIdx.x;
  float v0 = row[t], v1 = row[t+256], v2 = row[t+512];
  float sum = v0+v1+v2;
  float sq  = v0*v0 + v1*v1 + v2*v2;
  for (int o = 32; o > 0; o >>= 1){ sum += __shfl_xor(sum, o); sq += __shfl_xor(sq, o); }
  __shared__ float s1[4], s2[4];
  int wv = t >> 6;
  if ((t & 63) == 0){ s1[wv] = sum; s2[wv] = sq; }
  __syncthreads();
  sum = s1[0]+s1[1]+s1[2]+s1[3];
  sq  = s2[0]+s2[1]+s2[2]+s2[3];
  float mean = sum * (1.0f/DMODEL);
  float var  = sq  * (1.0f/DMODEL) - mean*mean;
  float inv = rsqrtf(var + 1e-5f);
  float* orow = outF + (long)s*DMODEL;
  unsigned short* brow = outBF ? outBF + (long)s*DMODEL : (unsigned short*)0;
  #pragma unroll
  for (int j = 0; j < 3; j++){
    int d = t + j*256;
    float y = (row[d] - mean) * inv * g[d] + b[d];
    orow[d] = y;
    if (brow) brow[d] = f2bf(y);
  }
}

// ---------------- gate: fp32 logits, top-2, softmax, routing records ----------------
__global__ __launch_bounds__(64) void gate_kernel(const float* __restrict__ x,
    const float* __restrict__ gw, const float* __restrict__ gb,
    float* __restrict__ gate_out, int* __restrict__ tok_e,
    float* __restrict__ tok_w, int* __restrict__ cnt){
  int s = blockIdx.x;
  int lane = threadIdx.x;
  float acc[NEXP];
  #pragma unroll
  for (int e = 0; e < NEXP; e++) acc[e] = 0.f;
  const float* xr = x + (long)s*DMODEL;
  for (int d = lane; d < DMODEL; d += 64){
    float xv = xr[d];
    const float* wr = gw + (long)d*NEXP;
    #pragma unroll
    for (int e = 0; e < NEXP; e++) acc[e] += xv * wr[e];
  }
  #pragma unroll
  for (int e = 0; e < NEXP; e++){
    float v = acc[e];
    for (int o = 32; o > 0; o >>= 1) v += __shfl_xor(v, o);
    acc[e] = v;
  }
  if (lane == 0){
    #pragma unroll
    for (int e = 0; e < NEXP; e++) acc[e] += gb[e];
    int i0 = 0;
    for (int e = 1; e < NEXP; e++) if (acc[e] > acc[i0]) i0 = e;
    int i1 = -1;
    for (int e = 0; e < NEXP; e++) if (e != i0 && (i1 < 0 || acc[e] > acc[i1])) i1 = e;
    float e1 = expf(acc[i1] - acc[i0]);
    float inv = 1.f / (1.f + e1);
    float w0 = inv, w1 = e1 * inv;
    float* go = gate_out + (long)s*NEXP;
    #pragma unroll
    for (int e = 0; e < NEXP; e++) go[e] = 0.f;
    go[i0] = w0; go[i1] = w1;
    tok_e[s*2] = i0; tok_e[s*2+1] = i1;
    tok_w[s*2] = w0; tok_w[s*2+1] = w1;
    atomicAdd(&cnt[i0], 1);
    atomicAdd(&cnt[i1], 1);
  }
}

__global__ void scan_kernel(const int* __restrict__ cnt, int* __restrict__ offs){
  if (threadIdx.x == 0 && blockIdx.x == 0){
    int s = 0;
    for (int e = 0; e < NEXP; e++){ offs[e] = s; s += cnt[e]; }
  }
}

__global__ __launch_bounds__(256) void scatter_kernel(const int* __restrict__ tok_e,
    const float* __restrict__ tok_w, const int* __restrict__ offs, int* __restrict__ fill,
    int* __restrict__ pair_token, float* __restrict__ pair_w){
  int t = blockIdx.x*256 + threadIdx.x;
  if (t >= S_LEN) return;
  #pragma unroll
  for (int sl = 0; sl < 2; sl++){
    int e = tok_e[t*2+sl];
    int pos = atomicAdd(&fill[e], 1);
    int pi = offs[e] + pos;
    pair_token[pi] = t;
    pair_w[pi] = tok_w[t*2+sl];
  }
}

// ---------------- host launch ----------------
extern "C" void kernel_launch(void* const* d_in, const int* in_sizes, int n_in,
                              void* d_out, int out_size, void* d_ws, size_t ws_size,
                              hipStream_t stream){
  (void)in_sizes; (void)n_in; (void)out_size; (void)ws_size;
  const float* hidden = (const float*)d_in[0];
  const float* Wq  = (const float*)d_in[1];
  const float* bq  = (const float*)d_in[2];
  const float* Wk  = (const float*)d_in[3];
  const float* bk  = (const float*)d_in[4];
  const float* Wv  = (const float*)d_in[5];
  const float* bv  = (const float*)d_in[6];
  const float* Wo  = (const float*)d_in[7];
  const float* bo  = (const float*)d_in[8];
  const float* ln1g = (const float*)d_in[9];
  const float* ln1b = (const float*)d_in[10];
  const float* gateW = (const float*)d_in[11];
  const float* gateB = (const float*)d_in[12];
  const float* W1e = (const float*)d_in[13];
  const float* b1e = (const float*)d_in[14];
  const float* W2e = (const float*)d_in[15];
  const float* b2e = (const float*)d_in[16];
  const float* Wd  = (const float*)d_in[17];
  const float* bd  = (const float*)d_in[18];
  const float* ln2g = (const float*)d_in[19];
  const float* ln2b = (const float*)d_in[20];

  float* outL = (float*)d_out;
  float* outG = outL + (size_t)S_LEN*DMODEL;

  const size_t SD = (size_t)S_LEN*DMODEL;
  char* base = (char*)d_ws;
  size_t off = 0;
  auto alloc = [&](size_t bytes)->void*{
    void* r = base + off;
    off = (off + bytes + 255) & ~(size_t)255;
    return r;
  };
  unsigned short* x_hi    = (unsigned short*)alloc(SD*2);
  unsigned short* x_lo    = (unsigned short*)alloc(SD*2);
  unsigned short* wqkv_hi = (unsigned short*)alloc((size_t)2304*768*2);
  unsigned short* wqkv_lo = (unsigned short*)alloc((size_t)2304*768*2);
  unsigned short* wo_hi   = (unsigned short*)alloc((size_t)768*768*2);
  unsigned short* wo_lo   = (unsigned short*)alloc((size_t)768*768*2);
  unsigned short* wd_bf   = (unsigned short*)alloc((size_t)768*768*2);
  unsigned short* w1_bf   = (unsigned short*)alloc((size_t)NEXP*FDIM*DMODEL*2);
  unsigned short* w2_bf   = (unsigned short*)alloc((size_t)NEXP*FDIM*DMODEL*2);
  float* Qf = (float*)alloc(SD*4);
  float* Kf = (float*)alloc(SD*4);
  float* Vf = (float*)alloc(SD*4);
  unsigned short* attn_hi = (unsigned short*)alloc(SD*2);
  unsigned short* attn_lo = (unsigned short*)alloc(SD*2);
  float* preLN1    = (float*)alloc(SD*4);
  float* attnout_f = (float*)alloc(SD*4);
  unsigned short* attnout_bf = (unsigned short*)alloc(SD*2);
  int*   tok_e = (int*)alloc(2*S_LEN*4);
  float* tok_w = (float*)alloc(2*S_LEN*4);
  int*   cnt   = (int*)alloc(32*4);      // cnt[0:8], fill at +8
  int*   fill  = cnt + 8;
  int*   offs  = (int*)alloc(32*4);
  int*   pair_token = (int*)alloc(NPAIR*4);
  float* pair_w     = (float*)alloc(NPAIR*4);
  unsigned short* Hbuf = (unsigned short*)alloc((size_t)NPAIR*FDIM*2);
  // aliases (Q/K/V dead after attention; preLN1 dead after LN1):
  float* moe_f = Qf;
  unsigned short* moe_bf = (unsigned short*)Kf;
  float* preLN2 = preLN1;

  // 1. split hidden -> bf16 hi/lo
  split_kernel<<<dim3((unsigned)(SD/256)), dim3(256), 0, stream>>>(hidden, x_hi, x_lo, (int)SD);
  // 2. weight transposes/converts
  transp_kernel<1><<<dim3(24,24,1), dim3(32,8), 0, stream>>>(Wq, wqkv_hi,           wqkv_lo,           DMODEL, DMODEL, 0, 0);
  transp_kernel<1><<<dim3(24,24,1), dim3(32,8), 0, stream>>>(Wk, wqkv_hi+768*768,   wqkv_lo+768*768,   DMODEL, DMODEL, 0, 0);
  transp_kernel<1><<<dim3(24,24,1), dim3(32,8), 0, stream>>>(Wv, wqkv_hi+2*768*768, wqkv_lo+2*768*768, DMODEL, DMODEL, 0, 0);
  transp_kernel<1><<<dim3(24,24,1), dim3(32,8), 0, stream>>>(Wo, wo_hi, wo_lo, DMODEL, DMODEL, 0, 0);
  transp_kernel<0><<<dim3(24,24,1), dim3(32,8), 0, stream>>>(Wd, wd_bf, nullptr, DMODEL, DMODEL, 0, 0);
  transp_kernel<0><<<dim3(96,24,NEXP), dim3(32,8), 0, stream>>>(W1e, w1_bf, nullptr, DMODEL, FDIM, (long)DMODEL*FDIM, (long)DMODEL*FDIM);
  transp_kernel<0><<<dim3(24,96,NEXP), dim3(32,8), 0, stream>>>(W2e, w2_bf, nullptr, FDIM, DMODEL, (long)DMODEL*FDIM, (long)DMODEL*FDIM);

  // 3. QKV projection (split-precision), writes fp32 Q(scaled)/K/V in [h][s][64]
  GemmP pq = {};
  pq.A = x_hi; pq.Alo = x_lo; pq.B = wqkv_hi; pq.Blo = wqkv_lo;
  pq.M = S_LEN; pq.N = 2304; pq.K = DMODEL;
  pq.bias = bq; pq.bias2 = bk; pq.bias3 = bv;
  pq.outQ = Qf; pq.outK = Kf; pq.outV = Vf;
  gemm_bt<0,2><<<dim3(18,32,1), dim3(256), 0, stream>>>(pq);

  // 4. attention (fp32) -> attn hi/lo bf16 planes
  attn_kernel<<<dim3(16,NHEADS,4), dim3(256), 0, stream>>>(Qf, Kf, Vf, attn_hi, attn_lo);

  // 5. Wo projection + bias + residual -> preLN1 (fp32)
  GemmP pw = {};
  pw.A = attn_hi; pw.Alo = attn_lo; pw.B = wo_hi; pw.Blo = wo_lo;
  pw.M = S_LEN; pw.N = DMODEL; pw.K = DMODEL;
  pw.bias = bo; pw.resid = hidden; pw.outF = preLN1;
  gemm_bt<1,2><<<dim3(6,32,1), dim3(256), 0, stream>>>(pw);

  // 6. LN1 -> attnout (fp32 + bf16)
  ln_kernel<<<dim3(S_LEN), dim3(256), 0, stream>>>(preLN1, ln1g, ln1b, attnout_f, attnout_bf);

  // 7. zero counters + moe accumulator
  hipMemsetAsync(cnt, 0, 64, stream);
  hipMemsetAsync(moe_f, 0, SD*4, stream);

  // 8. gate + routing
  gate_kernel<<<dim3(S_LEN), dim3(64), 0, stream>>>(attnout_f, gateW, gateB, outG, tok_e, tok_w, cnt);
  scan_kernel<<<dim3(1), dim3(64), 0, stream>>>(cnt, offs);
  scatter_kernel<<<dim3(S_LEN/256), dim3(256), 0, stream>>>(tok_e, tok_w, offs, fill, pair_token, pair_w);

  // 9. MoE expert GEMMs (top-2 sparse)
  GemmP p1 = {};
  p1.A = attnout_bf; p1.B = w1_bf; p1.M = S_LEN; p1.N = FDIM; p1.K = DMODEL;
  p1.bias = b1e; p1.outBF = Hbuf;
  p1.pair_token = pair_token; p1.cnt = cnt; p1.offs = offs;
  gemm_bt<2,1><<<dim3(24,32,NEXP), dim3(256), 0, stream>>>(p1);

  GemmP p2 = {};
  p2.A = Hbuf; p2.B = w2_bf; p2.M = S_LEN; p2.N = DMODEL; p2.K = FDIM;
  p2.bias = b2e; p2.outF = moe_f;
  p2.pair_token = pair_token; p2.pair_w = pair_w; p2.cnt = cnt; p2.offs = offs;
  gemm_bt<3,1><<<dim3(6,32,NEXP), dim3(256), 0, stream>>>(p2);

  // 10. moe -> bf16, Wd + bias + residual(attention_output) -> preLN2
  cast_kernel<<<dim3((unsigned)(SD/256)), dim3(256), 0, stream>>>(moe_f, moe_bf, (int)SD);
  GemmP pd = {};
  pd.A = moe_bf; pd.B = wd_bf; pd.M = S_LEN; pd.N = DMODEL; pd.K = DMODEL;
  pd.bias = bd; pd.resid = attnout_f; pd.outF = preLN2;
  gemm_bt<4,1><<<dim3(6,32,1), dim3(256), 0, stream>>>(pd);

  // 11. LN2 -> layer_output
  ln_kernel<<<dim3(S_LEN), dim3(256), 0, stream>>>(preLN2, ln2g, ln2b, outL, nullptr);
}

// Round 2
// 1074.014 us; speedup vs baseline: 1.6356x; 1.6356x over previous
//
#include <hip/hip_runtime.h>
#include <hip/hip_bf16.h>
#include <math.h>

#define S_LEN 4096
#define DMODEL 768
#define NHEADS 12
#define DH 64
#define FDIM 3072
#define NEXP 7
#define NPAIR (2*S_LEN)

typedef __bf16 bf16x8 __attribute__((ext_vector_type(8)));
typedef float f32x4 __attribute__((ext_vector_type(4)));

__device__ __forceinline__ unsigned short f2bf(float f){
  union { float f; unsigned u; } v; v.f = f;
  unsigned r = v.u + 0x7fffu + ((v.u >> 16) & 1u);
  return (unsigned short)(r >> 16);
}
__device__ __forceinline__ float bf2f(unsigned short h){
  union { unsigned u; float f; } v; v.u = ((unsigned)h) << 16;
  return v.f;
}
__device__ __forceinline__ float gelu_f(float x){
  return 0.5f * x * (1.0f + erff(x * 0.7071067811865475f));
}
__device__ __forceinline__ f32x4 mfma16(bf16x8 a, bf16x8 b, f32x4 c){
  return __builtin_amdgcn_mfma_f32_16x16x32_bf16(a, b, c, 0, 0, 0);
}
// async global->LDS, 16 B per lane. LDS side must be wave-uniform base + lane*16.
__device__ __forceinline__ void glds16(const void* g, void* l){
  __builtin_amdgcn_global_load_lds((const __attribute__((address_space(1))) unsigned*)g,
                                   (__attribute__((address_space(3))) unsigned*)l, 16, 0, 0);
}

// ---------------- elementwise fp32 -> bf16 hi/lo split ----------------
__global__ __launch_bounds__(256) void split_kernel(const float* __restrict__ in,
    unsigned short* __restrict__ hi, unsigned short* __restrict__ lo, int n){
  int i = blockIdx.x*256 + threadIdx.x;
  if (i >= n) return;
  float v = in[i];
  unsigned short h = f2bf(v);
  hi[i] = h;
  lo[i] = f2bf(v - bf2f(h));
}

// ---------------- tiled transpose + convert: in [mat][R][C] f32 -> out [mat][C][R] bf16 (hi[,lo]) ----------------
template<int SPLIT>
__global__ __launch_bounds__(256) void transp_kernel(const float* __restrict__ in,
    unsigned short* __restrict__ hi, unsigned short* __restrict__ lo,
    int R, int C, long inStride, long outStride){
  const float* ip = in + (long)blockIdx.z * inStride;
  long ob = (long)blockIdx.z * outStride;
  __shared__ float tile[32][33];
  int c0 = blockIdx.x*32, r0 = blockIdx.y*32;
  for (int i = threadIdx.y; i < 32; i += 8)
    tile[i][threadIdx.x] = ip[(long)(r0+i)*C + c0 + threadIdx.x];
  __syncthreads();
  for (int i = threadIdx.y; i < 32; i += 8){
    float v = tile[threadIdx.x][i];
    long oidx = ob + (long)(c0+i)*R + r0 + threadIdx.x;
    unsigned short h = f2bf(v);
    hi[oidx] = h;
    if (SPLIT) lo[oidx] = f2bf(v - bf2f(h));
  }
}

// ---------------- generic 128x128x32 bf16 MFMA GEMM, B^T ("Bt[n][k]") layout ----------------
// MODE: 0=QKV  1=WO  2=MOE1(gather)  3=MOE2(per-pair store)  4=WD
struct GemmP {
  const unsigned short* A;
  const unsigned short* Alo;
  const unsigned short* B;
  const unsigned short* Blo;
  int M, N, K;
  const float* bias;  const float* bias2; const float* bias3;
  const float* resid;
  float* outF;
  unsigned short* outBF;
  float* outQ; float* outK; float* outV;
  const int* pair_token;
  const float* pair_w;
  const int* cnt;
  const int* offs;
};

template<int MODE, int PLANES>
__global__ __launch_bounds__(256, 2) void gemm_bt(GemmP p){
  const int tid  = threadIdx.x;
  const int lane = tid & 63;
  const int wave = tid >> 6;
  const int quad = lane >> 4;
  const int ln   = lane & 15;
  const int wr = wave >> 1, wc = wave & 1;
  const int bn0 = blockIdx.x * 128;
  const int bm0 = blockIdx.y * 128;
  const int K = p.K;

  int e = 0, eoff = 0, Mloc = p.M;
  if (MODE == 2 || MODE == 3){
    e = blockIdx.z;
    eoff = p.offs[e];
    Mloc = p.cnt[e];
    if (bm0 >= Mloc) return;
  }
  const unsigned short* Bp = p.B + ((MODE == 2 || MODE == 3) ? (long)e * FDIM * DMODEL : 0);

  // per-thread source addresses for the two 16B staging chunks of A and B
  long aoff[2]; long boff[2]; int koff[2];
  #pragma unroll
  for (int j = 0; j < 2; j++){
    int c = tid + j*256;
    int row = c >> 2;
    koff[j] = (c & 3) * 8;
    if (MODE == 2){
      int r = bm0 + row; if (r >= Mloc) r = Mloc - 1;
      aoff[j] = (long)p.pair_token[eoff + r] * K;
    } else if (MODE == 3){
      int r = bm0 + row; if (r >= Mloc) r = Mloc - 1;
      aoff[j] = (long)(eoff + r) * K;
    } else {
      aoff[j] = (long)(bm0 + row) * K;
    }
    boff[j] = (long)(bn0 + row) * K;
  }

  __shared__ __align__(16) unsigned short As[PLANES][128*32];
  __shared__ __align__(16) unsigned short Bs[PLANES][128*32];

  f32x4 zero4 = {0.f, 0.f, 0.f, 0.f};
  f32x4 acc[4][4];
  #pragma unroll
  for (int i = 0; i < 4; i++)
    #pragma unroll
    for (int j = 0; j < 4; j++) acc[i][j] = zero4;

  for (int k0 = 0; k0 < K; k0 += 32){
    __syncthreads();   // prior consumers of As/Bs done
    #pragma unroll
    for (int j = 0; j < 2; j++){
      int c = tid + j*256;
      glds16(p.A + aoff[j] + k0 + koff[j], &As[0][c*8]);
      glds16(Bp  + boff[j] + k0 + koff[j], &Bs[0][c*8]);
      if (PLANES == 2){
        glds16(p.Alo + aoff[j] + k0 + koff[j], &As[1][c*8]);
        glds16(p.Blo + boff[j] + k0 + koff[j], &Bs[1][c*8]);
      }
    }
    __syncthreads();   // drains vmcnt: LDS tiles valid
    bf16x8 af[PLANES][4], bfr[PLANES][4];
    #pragma unroll
    for (int mt = 0; mt < 4; mt++)
      #pragma unroll
      for (int pl = 0; pl < PLANES; pl++)
        af[pl][mt] = *(const bf16x8*)&As[pl][(wr*64 + mt*16 + ln)*32 + quad*8];
    #pragma unroll
    for (int nt = 0; nt < 4; nt++)
      #pragma unroll
      for (int pl = 0; pl < PLANES; pl++)
        bfr[pl][nt] = *(const bf16x8*)&Bs[pl][(wc*64 + nt*16 + ln)*32 + quad*8];
    #pragma unroll
    for (int mt = 0; mt < 4; mt++){
      #pragma unroll
      for (int nt = 0; nt < 4; nt++){
        acc[mt][nt] = mfma16(af[0][mt], bfr[0][nt], acc[mt][nt]);
        if (PLANES == 2){
          acc[mt][nt] = mfma16(af[0][mt], bfr[1][nt], acc[mt][nt]);
          acc[mt][nt] = mfma16(af[1][mt], bfr[0][nt], acc[mt][nt]);
        }
      }
    }
  }

  #pragma unroll
  for (int mt = 0; mt < 4; mt++){
    #pragma unroll
    for (int nt = 0; nt < 4; nt++){
      #pragma unroll
      for (int r = 0; r < 4; r++){
        int gm = bm0 + wr*64 + mt*16 + quad*4 + r;
        int gn = bn0 + wc*64 + nt*16 + ln;
        float v = acc[mt][nt][r];
        if (MODE == 0){
          int which = gn >= 1536 ? 2 : (gn >= 768 ? 1 : 0);
          int nn = gn - which*768;
          int hh = nn >> 6, dh = nn & 63;
          float* dst;
          if (which == 0){ v = (v + p.bias[nn]) * 0.125f; dst = p.outQ; }
          else if (which == 1){ v = v + p.bias2[nn]; dst = p.outK; }
          else { v = v + p.bias3[nn]; dst = p.outV; }
          dst[((long)hh*S_LEN + gm)*64 + dh] = v;
        } else if (MODE == 1 || MODE == 4){
          long i = (long)gm*DMODEL + gn;
          p.outF[i] = v + p.bias[gn] + p.resid[i];
        } else if (MODE == 2){
          if (gm < Mloc){
            v = gelu_f(v + p.bias[(long)e*FDIM + gn]);
            p.outBF[(long)(eoff + gm)*FDIM + gn] = f2bf(v);
          }
        } else if (MODE == 3){
          if (gm < Mloc){
            int pi = eoff + gm;
            p.outF[(long)pi*DMODEL + gn] = v + p.bias[(long)e*DMODEL + gn];
          }
        }
      }
    }
  }
}

// ---------------- fp32 sliding-window attention (flash-style, online softmax) ----------------
// grid (16 chunks, 12 heads, 4 sub-blocks of 64 queries); block 256
__global__ __launch_bounds__(256) void attn_kernel(const float* __restrict__ Qf,
    const float* __restrict__ Kf, const float* __restrict__ Vf,
    unsigned short* __restrict__ attn_hi, unsigned short* __restrict__ attn_lo){
  const int c  = blockIdx.x;
  const int h  = blockIdx.y;
  const int qb = blockIdx.z;
  const int tid = threadIdx.x;
  const int q0abs = c*256 + qb*64;

  __shared__ __align__(16) float Ks[64*64];   // [key][d]
  __shared__ __align__(16) float Vs[64*64];   // [key][d]
  __shared__ float Ps[64*67];                 // [q][key], stride 67 (bank-spread)
  __shared__ float mA[64], alphaA[64], lA[64];
  __shared__ float pmaxA[64*8], psumA[64*8];

  const int qg = tid & 31;        // 2 queries each
  const int kg = tid >> 5;        // 8 keys (S phase) / 8 dims (PV phase)
  const int qa0 = q0abs + qg*2;
  const float* qrow0 = Qf + ((long)h*S_LEN + qa0)*64;
  const float* qrow1 = qrow0 + 64;

  float m_st = -1e30f, l_st = 0.f;   // valid for tid<64 (row threads)
  float O0[8], O1[8];
  #pragma unroll
  for (int j = 0; j < 8; j++){ O0[j] = 0.f; O1[j] = 0.f; }

  for (int kb = 0; kb < 12; kb++){
    const int kstart = c*256 - 256 + kb*64;
    __syncthreads();   // prior-iteration readers of Ks/Vs/Ps done
    // K/V tile -> LDS, async 16B/lane; clamped per 16B chunk (chunk stays in one row)
    #pragma unroll
    for (int pp = 0; pp < 4; pp++){
      int idx = pp*256 + tid;
      int row = idx >> 4;
      int ka = kstart + row;
      int kac = ka < 0 ? 0 : (ka >= S_LEN ? S_LEN-1 : ka);
      long gb = ((long)h*S_LEN + kac)*64 + (idx & 15)*4;
      glds16(Kf + gb, &Ks[idx*4]);
      glds16(Vf + gb, &Vs[idx*4]);
    }
    __syncthreads();
    // ---- scores: 2q x 8k per thread, raw scores + per-thread row max ----
    float s0[8], s1[8];
    #pragma unroll
    for (int j = 0; j < 8; j++){ s0[j] = 0.f; s1[j] = 0.f; }
    #pragma unroll 4
    for (int d4 = 0; d4 < 16; d4++){
      float4 q0 = *(const float4*)(qrow0 + d4*4);
      float4 q1 = *(const float4*)(qrow1 + d4*4);
      #pragma unroll
      for (int j = 0; j < 8; j++){
        float4 k4 = *(const float4*)&Ks[(kg*8+j)*64 + d4*4];
        s0[j] += q0.x*k4.x + q0.y*k4.y + q0.z*k4.z + q0.w*k4.w;
        s1[j] += q1.x*k4.x + q1.y*k4.y + q1.z*k4.z + q1.w*k4.w;
      }
    }
    float pm0 = -1e30f, pm1 = -1e30f;
    #pragma unroll
    for (int j = 0; j < 8; j++){
      int ka = kstart + kg*8 + j;
      bool ok = (ka >= 0) && (ka < S_LEN);
      bool v0 = ok && (ka >= qa0-256) && (ka <= qa0+256);
      bool v1 = ok && (ka >= qa0-255) && (ka <= qa0+257);
      float t0 = v0 ? s0[j] : -1e9f;
      float t1 = v1 ? s1[j] : -1e9f;
      Ps[(qg*2  )*67 + kg*8 + j] = t0;
      Ps[(qg*2+1)*67 + kg*8 + j] = t1;
      pm0 = fmaxf(pm0, t0);
      pm1 = fmaxf(pm1, t1);
    }
    pmaxA[(qg*2  )*8 + kg] = pm0;
    pmaxA[(qg*2+1)*8 + kg] = pm1;
    __syncthreads();
    // ---- tiny per-row phase: 8 fmax + 1 exp ----
    if (tid < 64){
      const float* pm = &pmaxA[tid*8];
      float bm = pm[0];
      #pragma unroll
      for (int j = 1; j < 8; j++) bm = fmaxf(bm, pm[j]);
      float mnew = fmaxf(m_st, bm);
      alphaA[tid] = __expf(m_st - mnew);
      mA[tid] = mnew;
      m_st = mnew;
    }
    __syncthreads();
    // ---- exp transform by all 256 threads + partial sums ----
    {
      float m0 = mA[qg*2], m1 = mA[qg*2+1];
      float ps0 = 0.f, ps1 = 0.f;
      float* r0 = &Ps[(qg*2)*67 + kg*8];
      float* r1 = r0 + 67;
      #pragma unroll
      for (int j = 0; j < 8; j++){
        float e0 = __expf(r0[j] - m0); r0[j] = e0; ps0 += e0;
        float e1 = __expf(r1[j] - m1); r1[j] = e1; ps1 += e1;
      }
      psumA[(qg*2  )*8 + kg] = ps0;
      psumA[(qg*2+1)*8 + kg] = ps1;
    }
    __syncthreads();
    if (tid < 64){
      const float* ps = &psumA[tid*8];
      float se = ps[0]+ps[1]+ps[2]+ps[3]+ps[4]+ps[5]+ps[6]+ps[7];
      l_st = l_st * alphaA[tid] + se;
    }
    // ---- PV accumulate: 2q x 8d per thread (Ps/alphaA valid since last barrier) ----
    {
      float a0 = alphaA[qg*2], a1 = alphaA[qg*2+1];
      #pragma unroll
      for (int j = 0; j < 8; j++){ O0[j] *= a0; O1[j] *= a1; }
      const float* p0r = &Ps[(qg*2)*67];
      const float* p1r = p0r + 67;
      for (int k = 0; k < 64; k++){
        float p0 = p0r[k], p1 = p1r[k];
        const float4* vr = (const float4*)&Vs[k*64 + kg*8];
        float4 va = vr[0], vb = vr[1];
        O0[0]+=p0*va.x; O0[1]+=p0*va.y; O0[2]+=p0*va.z; O0[3]+=p0*va.w;
        O0[4]+=p0*vb.x; O0[5]+=p0*vb.y; O0[6]+=p0*vb.z; O0[7]+=p0*vb.w;
        O1[0]+=p1*va.x; O1[1]+=p1*va.y; O1[2]+=p1*va.z; O1[3]+=p1*va.w;
        O1[4]+=p1*vb.x; O1[5]+=p1*vb.y; O1[6]+=p1*vb.z; O1[7]+=p1*vb.w;
      }
    }
  }
  if (tid < 64) lA[tid] = l_st;
  __syncthreads();
  {
    float i0 = 1.f / lA[qg*2], i1 = 1.f / lA[qg*2+1];
    long b0 = (long)qa0*DMODEL + h*64 + kg*8;
    #pragma unroll
    for (int j = 0; j < 8; j++){
      float o0 = O0[j]*i0, o1 = O1[j]*i1;
      unsigned short h0 = f2bf(o0);
      attn_hi[b0 + j] = h0;
      attn_lo[b0 + j] = f2bf(o0 - bf2f(h0));
      unsigned short h1 = f2bf(o1);
      attn_hi[b0 + DMODEL + j] = h1;
      attn_lo[b0 + DMODEL + j] = f2bf(o1 - bf2f(h1));
    }
  }
}

// ---------------- LayerNorm (fp32), optional bf16 copy ----------------
__global__ __launch_bounds__(256) void ln_kernel(const float* __restrict__ x,
    const float* __restrict__ g, const float* __restrict__ b,
    float* __restrict__ outF, unsigned short* __restrict__ outBF){
  int s = blockIdx.x;
  const float* row = x + (long)s*DMODEL;
  int t = threadIdx.x;
  float v0 = row[t], v1 = row[t+256], v2 = row[t+512];
  float sum = v0+v1+v2;
  float sq  = v0*v0 + v1*v1 + v2*v2;
  for (int o = 32; o > 0; o >>= 1){ sum += __shfl_xor(sum, o); sq += __shfl_xor(sq, o); }
  __shared__ float s1[4], s2[4];
  int wv = t >> 6;
  if ((t & 63) == 0){ s1[wv] = sum; s2[wv] = sq; }
  __syncthreads();
  sum = s1[0]+s1[1]+s1[2]+s1[3];
  sq  = s2[0]+s2[1]+s2[2]+s2[3];
  float mean = sum * (1.0f/DMODEL);
  float var  = sq  * (1.0f/DMODEL) - mean*mean;
  float inv = rsqrtf(var + 1e-5f);
  float* orow = outF + (long)s*DMODEL;
  unsigned short* brow = outBF ? outBF + (long)s*DMODEL : (unsigned short*)0;
  #pragma unroll
  for (int j = 0; j < 3; j++){
    int d = t + j*256;
    float y = (row[d] - mean) * inv * g[d] + b[d];
    orow[d] = y;
    if (brow) brow[d] = f2bf(y);
  }
}

// ---------------- gate: fp32 logits, top-2, softmax, routing records ----------------
__global__ __launch_bounds__(64) void gate_kernel(const float* __restrict__ x,
    const float* __restrict__ gw, const float* __restrict__ gb,
    float* __restrict__ gate_out, int* __restrict__ tok_e,
    float* __restrict__ tok_w, int* __restrict__ cnt){
  int s = blockIdx.x;
  int lane = threadIdx.x;
  float acc[NEXP];
  #pragma unroll
  for (int e = 0; e < NEXP; e++) acc[e] = 0.f;
  const float* xr = x + (long)s*DMODEL;
  for (int d = lane; d < DMODEL; d += 64){
    float xv = xr[d];
    const float* wr = gw + (long)d*NEXP;
    #pragma unroll
    for (int e = 0; e < NEXP; e++) acc[e] += xv * wr[e];
  }
  #pragma unroll
  for (int e = 0; e < NEXP; e++){
    float v = acc[e];
    for (int o = 32; o > 0; o >>= 1) v += __shfl_xor(v, o);
    acc[e] = v;
  }
  if (lane == 0){
    #pragma unroll
    for (int e = 0; e < NEXP; e++) acc[e] += gb[e];
    int i0 = 0;
    for (int e = 1; e < NEXP; e++) if (acc[e] > acc[i0]) i0 = e;
    int i1 = -1;
    for (int e = 0; e < NEXP; e++) if (e != i0 && (i1 < 0 || acc[e] > acc[i1])) i1 = e;
    float e1 = expf(acc[i1] - acc[i0]);
    float inv = 1.f / (1.f + e1);
    float w0 = inv, w1 = e1 * inv;
    float* go = gate_out + (long)s*NEXP;
    #pragma unroll
    for (int e = 0; e < NEXP; e++) go[e] = 0.f;
    go[i0] = w0; go[i1] = w1;
    tok_e[s*2] = i0; tok_e[s*2+1] = i1;
    tok_w[s*2] = w0; tok_w[s*2+1] = w1;
    atomicAdd(&cnt[i0], 1);
    atomicAdd(&cnt[i1], 1);
  }
}

__global__ void scan_kernel(const int* __restrict__ cnt, int* __restrict__ offs){
  if (threadIdx.x == 0 && blockIdx.x == 0){
    int s = 0;
    for (int e = 0; e < NEXP; e++){ offs[e] = s; s += cnt[e]; }
  }
}

__global__ __launch_bounds__(256) void scatter_kernel(const int* __restrict__ tok_e,
    const float* __restrict__ tok_w, const int* __restrict__ offs, int* __restrict__ fill,
    int* __restrict__ pair_token, float* __restrict__ pair_w, int* __restrict__ tok_pi){
  int t = blockIdx.x*256 + threadIdx.x;
  if (t >= S_LEN) return;
  #pragma unroll
  for (int sl = 0; sl < 2; sl++){
    int e = tok_e[t*2+sl];
    int pos = atomicAdd(&fill[e], 1);
    int pi = offs[e] + pos;
    pair_token[pi] = t;
    pair_w[pi] = tok_w[t*2+sl];
    tok_pi[t*2+sl] = pi;
  }
}

// ---------------- combine: moe[t] = w0*P[p0] + w1*P[p1] -> bf16 ----------------
__global__ __launch_bounds__(256) void combine_kernel(const float* __restrict__ Pbuf,
    const int* __restrict__ tok_pi, const float* __restrict__ tok_w,
    unsigned short* __restrict__ moe_bf){
  int t = blockIdx.x;
  int d = threadIdx.x;
  float w0 = tok_w[t*2], w1 = tok_w[t*2+1];
  long p0 = (long)tok_pi[t*2]   * DMODEL;
  long p1 = (long)tok_pi[t*2+1] * DMODEL;
  unsigned short* orow = moe_bf + (long)t*DMODEL;
  #pragma unroll
  for (int j = 0; j < 3; j++){
    int dd = d + j*256;
    orow[dd] = f2bf(w0*Pbuf[p0+dd] + w1*Pbuf[p1+dd]);
  }
}

// ---------------- host launch ----------------
extern "C" void kernel_launch(void* const* d_in, const int* in_sizes, int n_in,
                              void* d_out, int out_size, void* d_ws, size_t ws_size,
                              hipStream_t stream){
  (void)in_sizes; (void)n_in; (void)out_size; (void)ws_size;
  const float* hidden = (const float*)d_in[0];
  const float* Wq  = (const float*)d_in[1];
  const float* bq  = (const float*)d_in[2];
  const float* Wk  = (const float*)d_in[3];
  const float* bk  = (const float*)d_in[4];
  const float* Wv  = (const float*)d_in[5];
  const float* bv  = (const float*)d_in[6];
  const float* Wo  = (const float*)d_in[7];
  const float* bo  = (const float*)d_in[8];
  const float* ln1g = (const float*)d_in[9];
  const float* ln1b = (const float*)d_in[10];
  const float* gateW = (const float*)d_in[11];
  const float* gateB = (const float*)d_in[12];
  const float* W1e = (const float*)d_in[13];
  const float* b1e = (const float*)d_in[14];
  const float* W2e = (const float*)d_in[15];
  const float* b2e = (const float*)d_in[16];
  const float* Wd  = (const float*)d_in[17];
  const float* bd  = (const float*)d_in[18];
  const float* ln2g = (const float*)d_in[19];
  const float* ln2b = (const float*)d_in[20];

  float* outL = (float*)d_out;
  float* outG = outL + (size_t)S_LEN*DMODEL;

  const size_t SD = (size_t)S_LEN*DMODEL;
  char* base = (char*)d_ws;
  size_t off = 0;
  auto alloc = [&](size_t bytes)->void*{
    void* r = base + off;
    off = (off + bytes + 255) & ~(size_t)255;
    return r;
  };
  unsigned short* x_hi    = (unsigned short*)alloc(SD*2);
  unsigned short* x_lo    = (unsigned short*)alloc(SD*2);
  unsigned short* wqkv_hi = (unsigned short*)alloc((size_t)2304*768*2);
  unsigned short* wqkv_lo = (unsigned short*)alloc((size_t)2304*768*2);
  unsigned short* wo_hi   = (unsigned short*)alloc((size_t)768*768*2);
  unsigned short* wo_lo   = (unsigned short*)alloc((size_t)768*768*2);
  unsigned short* wd_bf   = (unsigned short*)alloc((size_t)768*768*2);
  unsigned short* w1_bf   = (unsigned short*)alloc((size_t)NEXP*FDIM*DMODEL*2);
  unsigned short* w2_bf   = (unsigned short*)alloc((size_t)NEXP*FDIM*DMODEL*2);
  float* Qf = (float*)alloc(SD*4);
  float* Kf = (float*)alloc(SD*4);
  float* Vf = (float*)alloc(SD*4);
  unsigned short* attn_hi = (unsigned short*)alloc(SD*2);
  unsigned short* attn_lo = (unsigned short*)alloc(SD*2);
  float* preLN1    = (float*)alloc(SD*4);
  float* attnout_f = (float*)alloc(SD*4);
  unsigned short* attnout_bf = (unsigned short*)alloc(SD*2);
  int*   tok_e = (int*)alloc(2*S_LEN*4);
  float* tok_w = (float*)alloc(2*S_LEN*4);
  int*   tok_pi = (int*)alloc(2*S_LEN*4);
  int*   cnt   = (int*)alloc(32*4);      // cnt[0:8], fill at +8
  int*   fill  = cnt + 8;
  int*   offs  = (int*)alloc(32*4);
  int*   pair_token = (int*)alloc(NPAIR*4);
  float* pair_w     = (float*)alloc(NPAIR*4);
  unsigned short* Hbuf = (unsigned short*)alloc((size_t)NPAIR*FDIM*2);
  // aliases: Q/K/V dead after attention. Pbuf (NPAIR x DMODEL fp32 = 2*SD*4 bytes)
  // spans Qf..Kf (contiguous, both SD*4 and 256-aligned). moe_bf aliases Vf.
  float* Pbuf = Qf;
  unsigned short* moe_bf = (unsigned short*)Vf;
  float* preLN2 = preLN1;

  // 1. split hidden -> bf16 hi/lo
  split_kernel<<<dim3((unsigned)(SD/256)), dim3(256), 0, stream>>>(hidden, x_hi, x_lo, (int)SD);
  // 2. weight transposes/converts
  transp_kernel<1><<<dim3(24,24,1), dim3(32,8), 0, stream>>>(Wq, wqkv_hi,           wqkv_lo,           DMODEL, DMODEL, 0, 0);
  transp_kernel<1><<<dim3(24,24,1), dim3(32,8), 0, stream>>>(Wk, wqkv_hi+768*768,   wqkv_lo+768*768,   DMODEL, DMODEL, 0, 0);
  transp_kernel<1><<<dim3(24,24,1), dim3(32,8), 0, stream>>>(Wv, wqkv_hi+2*768*768, wqkv_lo+2*768*768, DMODEL, DMODEL, 0, 0);
  transp_kernel<1><<<dim3(24,24,1), dim3(32,8), 0, stream>>>(Wo, wo_hi, wo_lo, DMODEL, DMODEL, 0, 0);
  transp_kernel<0><<<dim3(24,24,1), dim3(32,8), 0, stream>>>(Wd, wd_bf, nullptr, DMODEL, DMODEL, 0, 0);
  transp_kernel<0><<<dim3(96,24,NEXP), dim3(32,8), 0, stream>>>(W1e, w1_bf, nullptr, DMODEL, FDIM, (long)DMODEL*FDIM, (long)DMODEL*FDIM);
  transp_kernel<0><<<dim3(24,96,NEXP), dim3(32,8), 0, stream>>>(W2e, w2_bf, nullptr, FDIM, DMODEL, (long)DMODEL*FDIM, (long)DMODEL*FDIM);

  // 3. QKV projection (split-precision), writes fp32 Q(scaled)/K/V in [h][s][64]
  GemmP pq = {};
  pq.A = x_hi; pq.Alo = x_lo; pq.B = wqkv_hi; pq.Blo = wqkv_lo;
  pq.M = S_LEN; pq.N = 2304; pq.K = DMODEL;
  pq.bias = bq; pq.bias2 = bk; pq.bias3 = bv;
  pq.outQ = Qf; pq.outK = Kf; pq.outV = Vf;
  gemm_bt<0,2><<<dim3(18,32,1), dim3(256), 0, stream>>>(pq);

  // 4. attention (fp32) -> attn hi/lo bf16 planes
  attn_kernel<<<dim3(16,NHEADS,4), dim3(256), 0, stream>>>(Qf, Kf, Vf, attn_hi, attn_lo);

  // 5. Wo projection + bias + residual -> preLN1 (fp32)
  GemmP pw = {};
  pw.A = attn_hi; pw.Alo = attn_lo; pw.B = wo_hi; pw.Blo = wo_lo;
  pw.M = S_LEN; pw.N = DMODEL; pw.K = DMODEL;
  pw.bias = bo; pw.resid = hidden; pw.outF = preLN1;
  gemm_bt<1,2><<<dim3(6,32,1), dim3(256), 0, stream>>>(pw);

  // 6. LN1 -> attnout (fp32 + bf16)
  ln_kernel<<<dim3(S_LEN), dim3(256), 0, stream>>>(preLN1, ln1g, ln1b, attnout_f, attnout_bf);

  // 7. zero routing counters
  hipMemsetAsync(cnt, 0, 64, stream);

  // 8. gate + routing
  gate_kernel<<<dim3(S_LEN), dim3(64), 0, stream>>>(attnout_f, gateW, gateB, outG, tok_e, tok_w, cnt);
  scan_kernel<<<dim3(1), dim3(64), 0, stream>>>(cnt, offs);
  scatter_kernel<<<dim3(S_LEN/256), dim3(256), 0, stream>>>(tok_e, tok_w, offs, fill, pair_token, pair_w, tok_pi);

  // 9. MoE expert GEMMs (top-2 sparse)
  GemmP p1 = {};
  p1.A = attnout_bf; p1.B = w1_bf; p1.M = S_LEN; p1.N = FDIM; p1.K = DMODEL;
  p1.bias = b1e; p1.outBF = Hbuf;
  p1.pair_token = pair_token; p1.cnt = cnt; p1.offs = offs;
  gemm_bt<2,1><<<dim3(24,32,NEXP), dim3(256), 0, stream>>>(p1);

  GemmP p2 = {};
  p2.A = Hbuf; p2.B = w2_bf; p2.M = S_LEN; p2.N = DMODEL; p2.K = FDIM;
  p2.bias = b2e; p2.outF = Pbuf;
  p2.pair_token = pair_token; p2.pair_w = pair_w; p2.cnt = cnt; p2.offs = offs;
  gemm_bt<3,1><<<dim3(6,32,NEXP), dim3(256), 0, stream>>>(p2);

  // 10. combine pairs -> moe bf16; Wd + bias + residual(attention_output) -> preLN2
  combine_kernel<<<dim3(S_LEN), dim3(256), 0, stream>>>(Pbuf, tok_pi, tok_w, moe_bf);
  GemmP pd = {};
  pd.A = moe_bf; pd.B = wd_bf; pd.M = S_LEN; pd.N = DMODEL; pd.K = DMODEL;
  pd.bias = bd; pd.resid = attnout_f; pd.outF = preLN2;
  gemm_bt<4,1><<<dim3(6,32,1), dim3(256), 0, stream>>>(pd);

  // 11. LN2 -> layer_output
  ln_kernel<<<dim3(S_LEN), dim3(256), 0, stream>>>(preLN2, ln2g, ln2b, outL, nullptr);
}

// Round 3
// 832.722 us; speedup vs baseline: 2.1096x; 1.2898x over previous
//
#include <hip/hip_runtime.h>
#include <hip/hip_bf16.h>
#include <math.h>

#define S_LEN 4096
#define DMODEL 768
#define NHEADS 12
#define DH 64
#define FDIM 3072
#define NEXP 7
#define NPAIR (2*S_LEN)

typedef __bf16 bf16x8 __attribute__((ext_vector_type(8)));
typedef float f32x4 __attribute__((ext_vector_type(4)));

__device__ __forceinline__ unsigned short f2bf(float f){
  union { float f; unsigned u; } v; v.f = f;
  unsigned r = v.u + 0x7fffu + ((v.u >> 16) & 1u);
  return (unsigned short)(r >> 16);
}
__device__ __forceinline__ float bf2f(unsigned short h){
  union { unsigned u; float f; } v; v.u = ((unsigned)h) << 16;
  return v.f;
}
__device__ __forceinline__ float gelu_f(float x){
  return 0.5f * x * (1.0f + erff(x * 0.7071067811865475f));
}
__device__ __forceinline__ f32x4 mfma16(bf16x8 a, bf16x8 b, f32x4 c){
  return __builtin_amdgcn_mfma_f32_16x16x32_bf16(a, b, c, 0, 0, 0);
}
// async global->LDS, 16 B per lane. LDS side must be wave-uniform base + lane*16.
__device__ __forceinline__ void glds16(const void* g, void* l){
  __builtin_amdgcn_global_load_lds((const __attribute__((address_space(1))) unsigned*)g,
                                   (__attribute__((address_space(3))) unsigned*)l, 16, 0, 0);
}

// ---------------- elementwise fp32 -> bf16 hi/lo split ----------------
__global__ __launch_bounds__(256) void split_kernel(const float* __restrict__ in,
    unsigned short* __restrict__ hi, unsigned short* __restrict__ lo, int n){
  int i = blockIdx.x*256 + threadIdx.x;
  if (i >= n) return;
  float v = in[i];
  unsigned short h = f2bf(v);
  hi[i] = h;
  lo[i] = f2bf(v - bf2f(h));
}

// ---------------- tiled transpose + convert: in [mat][R][C] f32 -> out [mat][C][R] bf16 (hi[,lo]) ----------------
template<int SPLIT>
__global__ __launch_bounds__(256) void transp_kernel(const float* __restrict__ in,
    unsigned short* __restrict__ hi, unsigned short* __restrict__ lo,
    int R, int C, long inStride, long outStride){
  const float* ip = in + (long)blockIdx.z * inStride;
  long ob = (long)blockIdx.z * outStride;
  __shared__ float tile[32][33];
  int c0 = blockIdx.x*32, r0 = blockIdx.y*32;
  for (int i = threadIdx.y; i < 32; i += 8)
    tile[i][threadIdx.x] = ip[(long)(r0+i)*C + c0 + threadIdx.x];
  __syncthreads();
  for (int i = threadIdx.y; i < 32; i += 8){
    float v = tile[threadIdx.x][i];
    long oidx = ob + (long)(c0+i)*R + r0 + threadIdx.x;
    unsigned short h = f2bf(v);
    hi[oidx] = h;
    if (SPLIT) lo[oidx] = f2bf(v - bf2f(h));
  }
}

// ---------------- generic 128x128x32 bf16 MFMA GEMM, B^T ("Bt[n][k]") layout ----------------
// MODE: 0=QKV  1=WO  2=MOE1(gather)  3=MOE2(per-pair store)  4=WD
struct GemmP {
  const unsigned short* A;
  const unsigned short* Alo;
  const unsigned short* B;
  const unsigned short* Blo;
  int M, N, K;
  const float* bias;  const float* bias2; const float* bias3;
  const float* resid;
  float* outF;
  unsigned short* outBF;
  unsigned short *qhi,*qlo,*khi,*klo,*vthi,*vtlo;
  const int* pair_token;
  const float* pair_w;
  const int* cnt;
  const int* offs;
};

template<int MODE, int PLANES>
__global__ __launch_bounds__(256, 2) void gemm_bt(GemmP p){
  const int tid  = threadIdx.x;
  const int lane = tid & 63;
  const int wave = tid >> 6;
  const int quad = lane >> 4;
  const int ln   = lane & 15;
  const int wr = wave >> 1, wc = wave & 1;
  const int bn0 = blockIdx.x * 128;
  const int bm0 = blockIdx.y * 128;
  const int K = p.K;

  int e = 0, eoff = 0, Mloc = p.M;
  if (MODE == 2 || MODE == 3){
    e = blockIdx.z;
    eoff = p.offs[e];
    Mloc = p.cnt[e];
    if (bm0 >= Mloc) return;
  }
  const unsigned short* Bp = p.B + ((MODE == 2 || MODE == 3) ? (long)e * FDIM * DMODEL : 0);

  long aoff[2]; long boff[2]; int koff[2];
  #pragma unroll
  for (int j = 0; j < 2; j++){
    int c = tid + j*256;
    int row = c >> 2;
    koff[j] = (c & 3) * 8;
    if (MODE == 2){
      int r = bm0 + row; if (r >= Mloc) r = Mloc - 1;
      aoff[j] = (long)p.pair_token[eoff + r] * K;
    } else if (MODE == 3){
      int r = bm0 + row; if (r >= Mloc) r = Mloc - 1;
      aoff[j] = (long)(eoff + r) * K;
    } else {
      aoff[j] = (long)(bm0 + row) * K;
    }
    boff[j] = (long)(bn0 + row) * K;
  }

  __shared__ __align__(16) unsigned short As[PLANES][128*32];
  __shared__ __align__(16) unsigned short Bs[PLANES][128*32];

  f32x4 zero4 = {0.f, 0.f, 0.f, 0.f};
  f32x4 acc[4][4];
  #pragma unroll
  for (int i = 0; i < 4; i++)
    #pragma unroll
    for (int j = 0; j < 4; j++) acc[i][j] = zero4;

  for (int k0 = 0; k0 < K; k0 += 32){
    __syncthreads();
    #pragma unroll
    for (int j = 0; j < 2; j++){
      int c = tid + j*256;
      glds16(p.A + aoff[j] + k0 + koff[j], &As[0][c*8]);
      glds16(Bp  + boff[j] + k0 + koff[j], &Bs[0][c*8]);
      if (PLANES == 2){
        glds16(p.Alo + aoff[j] + k0 + koff[j], &As[1][c*8]);
        glds16(p.Blo + boff[j] + k0 + koff[j], &Bs[1][c*8]);
      }
    }
    __syncthreads();
    bf16x8 af[PLANES][4], bfr[PLANES][4];
    #pragma unroll
    for (int mt = 0; mt < 4; mt++)
      #pragma unroll
      for (int pl = 0; pl < PLANES; pl++)
        af[pl][mt] = *(const bf16x8*)&As[pl][(wr*64 + mt*16 + ln)*32 + quad*8];
    #pragma unroll
    for (int nt = 0; nt < 4; nt++)
      #pragma unroll
      for (int pl = 0; pl < PLANES; pl++)
        bfr[pl][nt] = *(const bf16x8*)&Bs[pl][(wc*64 + nt*16 + ln)*32 + quad*8];
    #pragma unroll
    for (int mt = 0; mt < 4; mt++){
      #pragma unroll
      for (int nt = 0; nt < 4; nt++){
        acc[mt][nt] = mfma16(af[0][mt], bfr[0][nt], acc[mt][nt]);
        if (PLANES == 2){
          acc[mt][nt] = mfma16(af[0][mt], bfr[1][nt], acc[mt][nt]);
          acc[mt][nt] = mfma16(af[1][mt], bfr[0][nt], acc[mt][nt]);
        }
      }
    }
  }

  #pragma unroll
  for (int mt = 0; mt < 4; mt++){
    #pragma unroll
    for (int nt = 0; nt < 4; nt++){
      #pragma unroll
      for (int r = 0; r < 4; r++){
        int gm = bm0 + wr*64 + mt*16 + quad*4 + r;
        int gn = bn0 + wc*64 + nt*16 + ln;
        float v = acc[mt][nt][r];
        if (MODE == 0){
          int which = gn >= 1536 ? 2 : (gn >= 768 ? 1 : 0);
          int nn = gn - which*768;
          int hh = nn >> 6, dh = nn & 63;
          if (which == 0){
            float q = (v + p.bias[nn]) * 0.125f;
            unsigned short qh = f2bf(q);
            long o = ((long)hh*S_LEN + gm)*64 + dh;
            p.qhi[o] = qh; p.qlo[o] = f2bf(q - bf2f(qh));
          } else if (which == 1){
            float kv = v + p.bias2[nn];
            unsigned short kh = f2bf(kv);
            long o = ((long)hh*S_LEN + gm)*64 + dh;
            p.khi[o] = kh; p.klo[o] = f2bf(kv - bf2f(kh));
          } else {
            float vv = v + p.bias3[nn];
            unsigned short vh = f2bf(vv);
            long o = ((long)hh*64 + dh)*S_LEN + gm;   // V^T: [h][d][s]
            p.vthi[o] = vh; p.vtlo[o] = f2bf(vv - bf2f(vh));
          }
        } else if (MODE == 1 || MODE == 4){
          long i = (long)gm*DMODEL + gn;
          p.outF[i] = v + p.bias[gn] + p.resid[i];
        } else if (MODE == 2){
          if (gm < Mloc){
            v = gelu_f(v + p.bias[(long)e*FDIM + gn]);
            p.outBF[(long)(eoff + gm)*FDIM + gn] = f2bf(v);
          }
        } else if (MODE == 3){
          if (gm < Mloc){
            int pi = eoff + gm;
            p.outF[(long)pi*DMODEL + gn] = v + p.bias[(long)e*DMODEL + gn];
          }
        }
      }
    }
  }
}

// ---------------- MFMA sliding-window attention, split bf16 hi/lo (fp32-grade) ----------------
// grid (16 chunks, 12 heads, 4 strips of 64 q); block 256 (4 waves x 16-q sub-strip)
__global__ __launch_bounds__(256) void attn_mfma(
    const unsigned short* __restrict__ Qhi, const unsigned short* __restrict__ Qlo,
    const unsigned short* __restrict__ Khi, const unsigned short* __restrict__ Klo,
    const unsigned short* __restrict__ Vthi, const unsigned short* __restrict__ Vtlo,
    unsigned short* __restrict__ attn_hi, unsigned short* __restrict__ attn_lo){
  const int c = blockIdx.x, h = blockIdx.y, qb = blockIdx.z;
  const int tid = threadIdx.x;
  const int lane = tid & 63, w = tid >> 6;
  const int quad = lane >> 4, ln = lane & 15;
  const int q0 = c*256 + qb*64;
  const int qw = q0 + w*16;

  // K/V tiles: [row][64] bf16, XOR chunk-swizzled (phys chunk = logical ^ (row&7))
  __shared__ __align__(16) unsigned short KsH[64*64], KsL[64*64];
  __shared__ __align__(16) unsigned short VsH[64*64], VsL[64*64];
  // P per wave: [16 q][72] (stride-72 pad)
  __shared__ __align__(16) unsigned short PsH[4][16*72], PsL[4][16*72];

  // Q A-frags (2 k-chunks, hi/lo) held in registers for the whole kernel
  bf16x8 qf_h[2], qf_l[2];
  {
    long qrow = ((long)h*S_LEN + qw + ln)*64 + quad*8;
    qf_h[0] = *(const bf16x8*)(Qhi + qrow);
    qf_h[1] = *(const bf16x8*)(Qhi + qrow + 32);
    qf_l[0] = *(const bf16x8*)(Qlo + qrow);
    qf_l[1] = *(const bf16x8*)(Qlo + qrow + 32);
  }

  float m_s[4], l_s[4];
  f32x4 Oc[4];
  f32x4 z4 = {0.f,0.f,0.f,0.f};
  #pragma unroll
  for (int r = 0; r < 4; r++){ m_s[r] = -1e30f; l_s[r] = 0.f; }
  #pragma unroll
  for (int nt = 0; nt < 4; nt++) Oc[nt] = z4;

  const unsigned short* KhiB = Khi + (long)h*S_LEN*64;
  const unsigned short* KloB = Klo + (long)h*S_LEN*64;
  const unsigned short* VhiB = Vthi + (long)h*64*S_LEN;
  const unsigned short* VloB = Vtlo + (long)h*64*S_LEN;

  for (int kb = 0; kb < 12; kb++){
    const int kstart = c*256 - 256 + kb*64;
    // block-uniform skips (range + band for the whole 64-q strip)
    if (kstart + 63 < 0 || kstart >= S_LEN) continue;
    if (kstart + 63 < q0 - 256 || kstart > q0 + 63 + 256) continue;
    __syncthreads();   // prior tile's consumers done
    #pragma unroll
    for (int p2 = 0; p2 < 2; p2++){
      int idx = p2*256 + tid;        // physical 16B-chunk index
      int row = idx >> 3;            // K: key row / V: dim row
      int pc  = idx & 7;             // physical chunk within row
      int lc  = pc ^ (row & 7);      // logical chunk (XOR swizzle)
      // K tile: row = key
      int ka = kstart + row;
      int kac = ka < 0 ? 0 : (ka > S_LEN-1 ? S_LEN-1 : ka);
      long gK = (long)kac*64 + lc*8;
      glds16(KhiB + gK, &KsH[idx*8]);
      glds16(KloB + gK, &KsL[idx*8]);
      // V tile: row = d, chunk = 8 keys
      int ks0 = kstart + lc*8;
      ks0 = ks0 < 0 ? 0 : (ks0 > S_LEN-8 ? S_LEN-8 : ks0);
      long gV = (long)row*S_LEN + ks0;
      glds16(VhiB + gV, &VsH[idx*8]);
      glds16(VloB + gV, &VsL[idx*8]);
    }
    __syncthreads();   // staging drained
    // wave-level skip (other waves still hit both barriers)
    if (kstart + 63 < qw - 256 || kstart > qw + 15 + 256) continue;

    // ---- S = Q K^T (3-plane split) ----
    f32x4 Sc[4];
    #pragma unroll
    for (int nt = 0; nt < 4; nt++) Sc[nt] = z4;
    #pragma unroll
    for (int kc = 0; kc < 2; kc++){
      bf16x8 bh[4], bl[4];
      #pragma unroll
      for (int nt = 0; nt < 4; nt++){
        int row = nt*16 + ln;
        int o = row*64 + (((kc*4 + quad) ^ (row & 7))*8);
        bh[nt] = *(const bf16x8*)&KsH[o];
        bl[nt] = *(const bf16x8*)&KsL[o];
      }
      #pragma unroll
      for (int nt = 0; nt < 4; nt++){
        Sc[nt] = mfma16(qf_h[kc], bh[nt], Sc[nt]);
        Sc[nt] = mfma16(qf_h[kc], bl[nt], Sc[nt]);
        Sc[nt] = mfma16(qf_l[kc], bh[nt], Sc[nt]);
      }
    }
    // ---- mask (row = quad*4+r, col = ln within 16-tile nt) ----
    bool interior = (kstart >= qw - 241) && (kstart <= qw + 193) &&
                    (kstart >= 0) && (kstart + 63 <= S_LEN - 1);
    if (!interior){
      #pragma unroll
      for (int nt = 0; nt < 4; nt++){
        int ka = kstart + nt*16 + ln;
        #pragma unroll
        for (int r = 0; r < 4; r++){
          int qa = qw + quad*4 + r;
          bool v = (ka >= 0) && (ka < S_LEN) && (ka >= qa - 256) && (ka <= qa + 256);
          if (!v) Sc[nt][r] = -3.0e38f;   // underflows to P=0; no-poison mask
        }
      }
    }
    // ---- online softmax: all state in registers ----
    float bm[4];
    #pragma unroll
    for (int r = 0; r < 4; r++)
      bm[r] = fmaxf(fmaxf(Sc[0][r], Sc[1][r]), fmaxf(Sc[2][r], Sc[3][r]));
    #pragma unroll
    for (int off = 1; off < 16; off <<= 1)
      #pragma unroll
      for (int r = 0; r < 4; r++) bm[r] = fmaxf(bm[r], __shfl_xor(bm[r], off));
    float al[4];
    #pragma unroll
    for (int r = 0; r < 4; r++){
      float mnew = fmaxf(m_s[r], bm[r]);
      al[r] = __expf(m_s[r] - mnew);
      m_s[r] = mnew;
    }
    float psum[4] = {0.f,0.f,0.f,0.f};
    #pragma unroll
    for (int nt = 0; nt < 4; nt++){
      #pragma unroll
      for (int r = 0; r < 4; r++){
        float pv = __expf(Sc[nt][r] - m_s[r]);
        psum[r] += pv;
        unsigned short ph = f2bf(pv);
        int o = (quad*4 + r)*72 + nt*16 + ln;
        PsH[w][o] = ph;
        PsL[w][o] = f2bf(pv - bf2f(ph));
      }
    }
    #pragma unroll
    for (int off = 1; off < 16; off <<= 1)
      #pragma unroll
      for (int r = 0; r < 4; r++) psum[r] += __shfl_xor(psum[r], off);
    #pragma unroll
    for (int r = 0; r < 4; r++) l_s[r] = l_s[r]*al[r] + psum[r];
    #pragma unroll
    for (int nt = 0; nt < 4; nt++)
      #pragma unroll
      for (int r = 0; r < 4; r++) Oc[nt][r] *= al[r];
    asm volatile("s_waitcnt lgkmcnt(0)" ::: "memory");   // P writes -> readable (wave-local)
    // ---- O += P V (3-plane split) ----
    #pragma unroll
    for (int kc = 0; kc < 2; kc++){
      bf16x8 ph = *(const bf16x8*)&PsH[w][ln*72 + kc*32 + quad*8];
      bf16x8 pl = *(const bf16x8*)&PsL[w][ln*72 + kc*32 + quad*8];
      #pragma unroll
      for (int nt = 0; nt < 4; nt++){
        int row = nt*16 + ln;
        int o = row*64 + (((kc*4 + quad) ^ (row & 7))*8);
        bf16x8 vh = *(const bf16x8*)&VsH[o];
        bf16x8 vl = *(const bf16x8*)&VsL[o];
        Oc[nt] = mfma16(ph, vh, Oc[nt]);
        Oc[nt] = mfma16(ph, vl, Oc[nt]);
        Oc[nt] = mfma16(pl, vh, Oc[nt]);
      }
    }
  }
  // ---- epilogue: O/l -> hi/lo planes in [s][768] ----
  float inv[4];
  #pragma unroll
  for (int r = 0; r < 4; r++) inv[r] = 1.f / l_s[r];
  #pragma unroll
  for (int nt = 0; nt < 4; nt++){
    #pragma unroll
    for (int r = 0; r < 4; r++){
      int qa = qw + quad*4 + r;
      long o = (long)qa*DMODEL + h*64 + nt*16 + ln;
      float ov = Oc[nt][r] * inv[r];
      unsigned short oh = f2bf(ov);
      attn_hi[o] = oh;
      attn_lo[o] = f2bf(ov - bf2f(oh));
    }
  }
}

// ---------------- LayerNorm (fp32), optional bf16 copy ----------------
__global__ __launch_bounds__(256) void ln_kernel(const float* __restrict__ x,
    const float* __restrict__ g, const float* __restrict__ b,
    float* __restrict__ outF, unsigned short* __restrict__ outBF){
  int s = blockIdx.x;
  const float* row = x + (long)s*DMODEL;
  int t = threadIdx.x;
  float v0 = row[t], v1 = row[t+256], v2 = row[t+512];
  float sum = v0+v1+v2;
  float sq  = v0*v0 + v1*v1 + v2*v2;
  for (int o = 32; o > 0; o >>= 1){ sum += __shfl_xor(sum, o); sq += __shfl_xor(sq, o); }
  __shared__ float s1[4], s2[4];
  int wv = t >> 6;
  if ((t & 63) == 0){ s1[wv] = sum; s2[wv] = sq; }
  __syncthreads();
  sum = s1[0]+s1[1]+s1[2]+s1[3];
  sq  = s2[0]+s2[1]+s2[2]+s2[3];
  float mean = sum * (1.0f/DMODEL);
  float var  = sq  * (1.0f/DMODEL) - mean*mean;
  float inv = rsqrtf(var + 1e-5f);
  float* orow = outF + (long)s*DMODEL;
  unsigned short* brow = outBF ? outBF + (long)s*DMODEL : (unsigned short*)0;
  #pragma unroll
  for (int j = 0; j < 3; j++){
    int d = t + j*256;
    float y = (row[d] - mean) * inv * g[d] + b[d];
    orow[d] = y;
    if (brow) brow[d] = f2bf(y);
  }
}

// ---------------- gate: fp32 logits, top-2, softmax, routing records ----------------
__global__ __launch_bounds__(64) void gate_kernel(const float* __restrict__ x,
    const float* __restrict__ gw, const float* __restrict__ gb,
    float* __restrict__ gate_out, int* __restrict__ tok_e,
    float* __restrict__ tok_w, int* __restrict__ cnt){
  int s = blockIdx.x;
  int lane = threadIdx.x;
  float acc[NEXP];
  #pragma unroll
  for (int e = 0; e < NEXP; e++) acc[e] = 0.f;
  const float* xr = x + (long)s*DMODEL;
  for (int d = lane; d < DMODEL; d += 64){
    float xv = xr[d];
    const float* wr = gw + (long)d*NEXP;
    #pragma unroll
    for (int e = 0; e < NEXP; e++) acc[e] += xv * wr[e];
  }
  #pragma unroll
  for (int e = 0; e < NEXP; e++){
    float v = acc[e];
    for (int o = 32; o > 0; o >>= 1) v += __shfl_xor(v, o);
    acc[e] = v;
  }
  if (lane == 0){
    #pragma unroll
    for (int e = 0; e < NEXP; e++) acc[e] += gb[e];
    int i0 = 0;
    for (int e = 1; e < NEXP; e++) if (acc[e] > acc[i0]) i0 = e;
    int i1 = -1;
    for (int e = 0; e < NEXP; e++) if (e != i0 && (i1 < 0 || acc[e] > acc[i1])) i1 = e;
    float e1 = expf(acc[i1] - acc[i0]);
    float inv = 1.f / (1.f + e1);
    float w0 = inv, w1 = e1 * inv;
    float* go = gate_out + (long)s*NEXP;
    #pragma unroll
    for (int e = 0; e < NEXP; e++) go[e] = 0.f;
    go[i0] = w0; go[i1] = w1;
    tok_e[s*2] = i0; tok_e[s*2+1] = i1;
    tok_w[s*2] = w0; tok_w[s*2+1] = w1;
    atomicAdd(&cnt[i0], 1);
    atomicAdd(&cnt[i1], 1);
  }
}

__global__ void scan_kernel(const int* __restrict__ cnt, int* __restrict__ offs){
  if (threadIdx.x == 0 && blockIdx.x == 0){
    int s = 0;
    for (int e = 0; e < NEXP; e++){ offs[e] = s; s += cnt[e]; }
  }
}

__global__ __launch_bounds__(256) void scatter_kernel(const int* __restrict__ tok_e,
    const float* __restrict__ tok_w, const int* __restrict__ offs, int* __restrict__ fill,
    int* __restrict__ pair_token, float* __restrict__ pair_w, int* __restrict__ tok_pi){
  int t = blockIdx.x*256 + threadIdx.x;
  if (t >= S_LEN) return;
  #pragma unroll
  for (int sl = 0; sl < 2; sl++){
    int e = tok_e[t*2+sl];
    int pos = atomicAdd(&fill[e], 1);
    int pi = offs[e] + pos;
    pair_token[pi] = t;
    pair_w[pi] = tok_w[t*2+sl];
    tok_pi[t*2+sl] = pi;
  }
}

// ---------------- combine: moe[t] = w0*P[p0] + w1*P[p1] -> bf16 ----------------
__global__ __launch_bounds__(256) void combine_kernel(const float* __restrict__ Pbuf,
    const int* __restrict__ tok_pi, const float* __restrict__ tok_w,
    unsigned short* __restrict__ moe_bf){
  int t = blockIdx.x;
  int d = threadIdx.x;
  float w0 = tok_w[t*2], w1 = tok_w[t*2+1];
  long p0 = (long)tok_pi[t*2]   * DMODEL;
  long p1 = (long)tok_pi[t*2+1] * DMODEL;
  unsigned short* orow = moe_bf + (long)t*DMODEL;
  #pragma unroll
  for (int j = 0; j < 3; j++){
    int dd = d + j*256;
    orow[dd] = f2bf(w0*Pbuf[p0+dd] + w1*Pbuf[p1+dd]);
  }
}

// ---------------- host launch ----------------
extern "C" void kernel_launch(void* const* d_in, const int* in_sizes, int n_in,
                              void* d_out, int out_size, void* d_ws, size_t ws_size,
                              hipStream_t stream){
  (void)in_sizes; (void)n_in; (void)out_size; (void)ws_size;
  const float* hidden = (const float*)d_in[0];
  const float* Wq  = (const float*)d_in[1];
  const float* bq  = (const float*)d_in[2];
  const float* Wk  = (const float*)d_in[3];
  const float* bk  = (const float*)d_in[4];
  const float* Wv  = (const float*)d_in[5];
  const float* bv  = (const float*)d_in[6];
  const float* Wo  = (const float*)d_in[7];
  const float* bo  = (const float*)d_in[8];
  const float* ln1g = (const float*)d_in[9];
  const float* ln1b = (const float*)d_in[10];
  const float* gateW = (const float*)d_in[11];
  const float* gateB = (const float*)d_in[12];
  const float* W1e = (const float*)d_in[13];
  const float* b1e = (const float*)d_in[14];
  const float* W2e = (const float*)d_in[15];
  const float* b2e = (const float*)d_in[16];
  const float* Wd  = (const float*)d_in[17];
  const float* bd  = (const float*)d_in[18];
  const float* ln2g = (const float*)d_in[19];
  const float* ln2b = (const float*)d_in[20];

  float* outL = (float*)d_out;
  float* outG = outL + (size_t)S_LEN*DMODEL;

  const size_t SD = (size_t)S_LEN*DMODEL;
  char* base = (char*)d_ws;
  size_t off = 0;
  auto alloc = [&](size_t bytes)->void*{
    void* r = base + off;
    off = (off + bytes + 255) & ~(size_t)255;
    return r;
  };
  unsigned short* x_hi    = (unsigned short*)alloc(SD*2);
  unsigned short* x_lo    = (unsigned short*)alloc(SD*2);
  unsigned short* wqkv_hi = (unsigned short*)alloc((size_t)2304*768*2);
  unsigned short* wqkv_lo = (unsigned short*)alloc((size_t)2304*768*2);
  unsigned short* wo_hi   = (unsigned short*)alloc((size_t)768*768*2);
  unsigned short* wo_lo   = (unsigned short*)alloc((size_t)768*768*2);
  unsigned short* wd_bf   = (unsigned short*)alloc((size_t)768*768*2);
  unsigned short* w1_bf   = (unsigned short*)alloc((size_t)NEXP*FDIM*DMODEL*2);
  unsigned short* w2_bf   = (unsigned short*)alloc((size_t)NEXP*FDIM*DMODEL*2);
  // QKV planes (bf16 hi/lo); contiguous region also reused later for Pbuf/moe_bf
  unsigned short* q_hi  = (unsigned short*)alloc(SD*2);
  unsigned short* q_lo  = (unsigned short*)alloc(SD*2);
  unsigned short* k_hi  = (unsigned short*)alloc(SD*2);
  unsigned short* k_lo  = (unsigned short*)alloc(SD*2);
  unsigned short* vt_hi = (unsigned short*)alloc(SD*2);
  unsigned short* vt_lo = (unsigned short*)alloc(SD*2);
  unsigned short* attn_hi = (unsigned short*)alloc(SD*2);
  unsigned short* attn_lo = (unsigned short*)alloc(SD*2);
  float* preLN1    = (float*)alloc(SD*4);
  float* attnout_f = (float*)alloc(SD*4);
  unsigned short* attnout_bf = (unsigned short*)alloc(SD*2);
  int*   tok_e = (int*)alloc(2*S_LEN*4);
  float* tok_w = (float*)alloc(2*S_LEN*4);
  int*   tok_pi = (int*)alloc(2*S_LEN*4);
  int*   cnt   = (int*)alloc(32*4);      // cnt[0:8], fill at +8
  int*   fill  = cnt + 8;
  int*   offs  = (int*)alloc(32*4);
  int*   pair_token = (int*)alloc(NPAIR*4);
  float* pair_w     = (float*)alloc(NPAIR*4);
  unsigned short* Hbuf = (unsigned short*)alloc((size_t)NPAIR*FDIM*2);
  // aliases: q/k/vt planes (6*SD*2 = 37.7MB contiguous) dead after attn_mfma.
  // Pbuf = NPAIR*DMODEL*4 = 25.2MB; moe_bf = SD*2 = 6.3MB placed after it.
  float* Pbuf = (float*)q_hi;
  unsigned short* moe_bf = (unsigned short*)((char*)q_hi + (size_t)NPAIR*DMODEL*4);
  float* preLN2 = preLN1;

  // 1. split hidden -> bf16 hi/lo
  split_kernel<<<dim3((unsigned)(SD/256)), dim3(256), 0, stream>>>(hidden, x_hi, x_lo, (int)SD);
  // 2. weight transposes/converts
  transp_kernel<1><<<dim3(24,24,1), dim3(32,8), 0, stream>>>(Wq, wqkv_hi,           wqkv_lo,           DMODEL, DMODEL, 0, 0);
  transp_kernel<1><<<dim3(24,24,1), dim3(32,8), 0, stream>>>(Wk, wqkv_hi+768*768,   wqkv_lo+768*768,   DMODEL, DMODEL, 0, 0);
  transp_kernel<1><<<dim3(24,24,1), dim3(32,8), 0, stream>>>(Wv, wqkv_hi+2*768*768, wqkv_lo+2*768*768, DMODEL, DMODEL, 0, 0);
  transp_kernel<1><<<dim3(24,24,1), dim3(32,8), 0, stream>>>(Wo, wo_hi, wo_lo, DMODEL, DMODEL, 0, 0);
  transp_kernel<0><<<dim3(24,24,1), dim3(32,8), 0, stream>>>(Wd, wd_bf, nullptr, DMODEL, DMODEL, 0, 0);
  transp_kernel<0><<<dim3(96,24,NEXP), dim3(32,8), 0, stream>>>(W1e, w1_bf, nullptr, DMODEL, FDIM, (long)DMODEL*FDIM, (long)DMODEL*FDIM);
  transp_kernel<0><<<dim3(24,96,NEXP), dim3(32,8), 0, stream>>>(W2e, w2_bf, nullptr, FDIM, DMODEL, (long)DMODEL*FDIM, (long)DMODEL*FDIM);

  // 3. QKV projection -> Q,K hi/lo [h][s][64]; V hi/lo transposed [h][d][s]
  GemmP pq = {};
  pq.A = x_hi; pq.Alo = x_lo; pq.B = wqkv_hi; pq.Blo = wqkv_lo;
  pq.M = S_LEN; pq.N = 2304; pq.K = DMODEL;
  pq.bias = bq; pq.bias2 = bk; pq.bias3 = bv;
  pq.qhi = q_hi; pq.qlo = q_lo; pq.khi = k_hi; pq.klo = k_lo; pq.vthi = vt_hi; pq.vtlo = vt_lo;
  gemm_bt<0,2><<<dim3(18,32,1), dim3(256), 0, stream>>>(pq);

  // 4. MFMA attention -> attn hi/lo bf16 planes
  attn_mfma<<<dim3(16,NHEADS,4), dim3(256), 0, stream>>>(q_hi, q_lo, k_hi, k_lo, vt_hi, vt_lo, attn_hi, attn_lo);

  // 5. Wo projection + bias + residual -> preLN1 (fp32)
  GemmP pw = {};
  pw.A = attn_hi; pw.Alo = attn_lo; pw.B = wo_hi; pw.Blo = wo_lo;
  pw.M = S_LEN; pw.N = DMODEL; pw.K = DMODEL;
  pw.bias = bo; pw.resid = hidden; pw.outF = preLN1;
  gemm_bt<1,2><<<dim3(6,32,1), dim3(256), 0, stream>>>(pw);

  // 6. LN1 -> attnout (fp32 + bf16)
  ln_kernel<<<dim3(S_LEN), dim3(256), 0, stream>>>(preLN1, ln1g, ln1b, attnout_f, attnout_bf);

  // 7. zero routing counters
  hipMemsetAsync(cnt, 0, 64, stream);

  // 8. gate + routing
  gate_kernel<<<dim3(S_LEN), dim3(64), 0, stream>>>(attnout_f, gateW, gateB, outG, tok_e, tok_w, cnt);
  scan_kernel<<<dim3(1), dim3(64), 0, stream>>>(cnt, offs);
  scatter_kernel<<<dim3(S_LEN/256), dim3(256), 0, stream>>>(tok_e, tok_w, offs, fill, pair_token, pair_w, tok_pi);

  // 9. MoE expert GEMMs (top-2 sparse)
  GemmP p1 = {};
  p1.A = attnout_bf; p1.B = w1_bf; p1.M = S_LEN; p1.N = FDIM; p1.K = DMODEL;
  p1.bias = b1e; p1.outBF = Hbuf;
  p1.pair_token = pair_token; p1.cnt = cnt; p1.offs = offs;
  gemm_bt<2,1><<<dim3(24,32,NEXP), dim3(256), 0, stream>>>(p1);

  GemmP p2 = {};
  p2.A = Hbuf; p2.B = w2_bf; p2.M = S_LEN; p2.N = DMODEL; p2.K = FDIM;
  p2.bias = b2e; p2.outF = Pbuf;
  p2.pair_token = pair_token; p2.pair_w = pair_w; p2.cnt = cnt; p2.offs = offs;
  gemm_bt<3,1><<<dim3(6,32,NEXP), dim3(256), 0, stream>>>(p2);

  // 10. combine pairs -> moe bf16; Wd + bias + residual(attention_output) -> preLN2
  combine_kernel<<<dim3(S_LEN), dim3(256), 0, stream>>>(Pbuf, tok_pi, tok_w, moe_bf);
  GemmP pd = {};
  pd.A = moe_bf; pd.B = wd_bf; pd.M = S_LEN; pd.N = DMODEL; pd.K = DMODEL;
  pd.bias = bd; pd.resid = attnout_f; pd.outF = preLN2;
  gemm_bt<4,1><<<dim3(6,32,1), dim3(256), 0, stream>>>(pd);

  // 11. LN2 -> layer_output
  ln_kernel<<<dim3(S_LEN), dim3(256), 0, stream>>>(preLN2, ln2g, ln2b, outL, nullptr);
}

// Round 4
// 831.497 us; speedup vs baseline: 2.1127x; 1.0015x over previous
//
#include <hip/hip_runtime.h>
#include <hip/hip_bf16.h>
#include <math.h>

#define S_LEN 4096
#define DMODEL 768
#define NHEADS 12
#define DH 64
#define FDIM 3072
#define NEXP 7
#define NPAIR (2*S_LEN)

typedef __bf16 bf16x8 __attribute__((ext_vector_type(8)));
typedef float f32x4 __attribute__((ext_vector_type(4)));

__device__ __forceinline__ unsigned short f2bf(float f){
  union { float f; unsigned u; } v; v.f = f;
  unsigned r = v.u + 0x7fffu + ((v.u >> 16) & 1u);
  return (unsigned short)(r >> 16);
}
__device__ __forceinline__ float bf2f(unsigned short h){
  union { unsigned u; float f; } v; v.u = ((unsigned)h) << 16;
  return v.f;
}
__device__ __forceinline__ float gelu_f(float x){
  return 0.5f * x * (1.0f + erff(x * 0.7071067811865475f));
}
__device__ __forceinline__ f32x4 mfma16(bf16x8 a, bf16x8 b, f32x4 c){
  return __builtin_amdgcn_mfma_f32_16x16x32_bf16(a, b, c, 0, 0, 0);
}
// async global->LDS, 16 B per lane. LDS side must be wave-uniform base + lane*16.
__device__ __forceinline__ void glds16(const void* g, void* l){
  __builtin_amdgcn_global_load_lds((const __attribute__((address_space(1))) unsigned*)g,
                                   (__attribute__((address_space(3))) unsigned*)l, 16, 0, 0);
}

// ---------------- elementwise fp32 -> bf16 hi/lo split ----------------
__global__ __launch_bounds__(256) void split_kernel(const float* __restrict__ in,
    unsigned short* __restrict__ hi, unsigned short* __restrict__ lo, int n){
  int i = blockIdx.x*256 + threadIdx.x;
  if (i >= n) return;
  float v = in[i];
  unsigned short h = f2bf(v);
  hi[i] = h;
  lo[i] = f2bf(v - bf2f(h));
}

// ---------------- tiled transpose + convert: in [mat][R][C] f32 -> out [mat][C][R] bf16 (hi[,lo]) ----------------
// store phase vectorized: each thread writes a ushort2 (pair of consecutive R-rows). Requires R even.
template<int SPLIT>
__global__ __launch_bounds__(256) void transp_kernel(const float* __restrict__ in,
    unsigned short* __restrict__ hi, unsigned short* __restrict__ lo,
    int R, int C, long inStride, long outStride){
  const float* ip = in + (long)blockIdx.z * inStride;
  long ob = (long)blockIdx.z * outStride;
  __shared__ float tile[32][33];
  int c0 = blockIdx.x*32, r0 = blockIdx.y*32;
  int tx = threadIdx.x, ty = threadIdx.y;
  for (int i = ty; i < 32; i += 8)
    tile[i][tx] = ip[(long)(r0+i)*C + c0 + tx];
  __syncthreads();
  int t  = tx + ty*32;
  int sx = t & 15;        // r-pair index
  int sc = t >> 4;        // col group
  #pragma unroll
  for (int j = 0; j < 2; j++){
    int cc = sc + j*16;
    float v0 = tile[sx*2][cc], v1 = tile[sx*2+1][cc];
    long oidx = ob + (long)(c0+cc)*R + r0 + sx*2;
    unsigned uh = (unsigned)f2bf(v0) | ((unsigned)f2bf(v1) << 16);
    *(unsigned*)(hi + oidx) = uh;
    if (SPLIT){
      unsigned ul = (unsigned)f2bf(v0 - bf2f(f2bf(v0))) | ((unsigned)f2bf(v1 - bf2f(f2bf(v1))) << 16);
      *(unsigned*)(lo + oidx) = ul;
    }
  }
}

// ---------------- generic 128x128x32 bf16 MFMA GEMM, B^T ("Bt[n][k]") layout ----------------
// MODE: 0=QKV  1=WO  2=MOE1(gather)  3=MOE2(per-pair store)  4=WD
struct GemmP {
  const unsigned short* A;
  const unsigned short* Alo;
  const unsigned short* B;
  const unsigned short* Blo;
  int M, N, K;
  const float* bias;  const float* bias2; const float* bias3;
  const float* resid;
  float* outF;
  unsigned short* outBF;
  unsigned short *qhi,*qlo,*khi,*klo,*vthi,*vtlo;
  const int* pair_token;
  const float* pair_w;
  const int* cnt;
  const int* offs;
};

template<int MODE, int PLANES>
__global__ __launch_bounds__(256, 2) void gemm_bt(GemmP p){
  const int tid  = threadIdx.x;
  const int lane = tid & 63;
  const int wave = tid >> 6;
  const int quad = lane >> 4;
  const int ln   = lane & 15;
  const int wr = wave >> 1, wc = wave & 1;
  const int bn0 = blockIdx.x * 128;
  const int bm0 = blockIdx.y * 128;
  const int K = p.K;

  long aoff[2]; long boff[2]; int koff[2];
  #pragma unroll
  for (int j = 0; j < 2; j++){
    int c = tid + j*256;
    int row = c >> 2;
    koff[j] = (c & 3) * 8;
    aoff[j] = (long)(bm0 + row) * K;
    boff[j] = (long)(bn0 + row) * K;
  }

  __shared__ __align__(16) unsigned short As[PLANES][128*32];
  __shared__ __align__(16) unsigned short Bs[PLANES][128*32];

  f32x4 zero4 = {0.f, 0.f, 0.f, 0.f};
  f32x4 acc[4][4];
  #pragma unroll
  for (int i = 0; i < 4; i++)
    #pragma unroll
    for (int j = 0; j < 4; j++) acc[i][j] = zero4;

  for (int k0 = 0; k0 < K; k0 += 32){
    __syncthreads();
    #pragma unroll
    for (int j = 0; j < 2; j++){
      int c = tid + j*256;
      glds16(p.A + aoff[j] + k0 + koff[j], &As[0][c*8]);
      glds16(p.B + boff[j] + k0 + koff[j], &Bs[0][c*8]);
      if (PLANES == 2){
        glds16(p.Alo + aoff[j] + k0 + koff[j], &As[1][c*8]);
        glds16(p.Blo + boff[j] + k0 + koff[j], &Bs[1][c*8]);
      }
    }
    __syncthreads();
    bf16x8 af[PLANES][4], bfr[PLANES][4];
    #pragma unroll
    for (int mt = 0; mt < 4; mt++)
      #pragma unroll
      for (int pl = 0; pl < PLANES; pl++)
        af[pl][mt] = *(const bf16x8*)&As[pl][(wr*64 + mt*16 + ln)*32 + quad*8];
    #pragma unroll
    for (int nt = 0; nt < 4; nt++)
      #pragma unroll
      for (int pl = 0; pl < PLANES; pl++)
        bfr[pl][nt] = *(const bf16x8*)&Bs[pl][(wc*64 + nt*16 + ln)*32 + quad*8];
    #pragma unroll
    for (int mt = 0; mt < 4; mt++){
      #pragma unroll
      for (int nt = 0; nt < 4; nt++){
        acc[mt][nt] = mfma16(af[0][mt], bfr[0][nt], acc[mt][nt]);
        if (PLANES == 2){
          acc[mt][nt] = mfma16(af[0][mt], bfr[1][nt], acc[mt][nt]);
          acc[mt][nt] = mfma16(af[1][mt], bfr[0][nt], acc[mt][nt]);
        }
      }
    }
  }

  #pragma unroll
  for (int mt = 0; mt < 4; mt++){
    #pragma unroll
    for (int nt = 0; nt < 4; nt++){
      #pragma unroll
      for (int r = 0; r < 4; r++){
        int gm = bm0 + wr*64 + mt*16 + quad*4 + r;
        int gn = bn0 + wc*64 + nt*16 + ln;
        float v = acc[mt][nt][r];
        if (MODE == 0){
          int which = gn >= 1536 ? 2 : (gn >= 768 ? 1 : 0);
          int nn = gn - which*768;
          int hh = nn >> 6, dh = nn & 63;
          if (which == 0){
            float q = (v + p.bias[nn]) * 0.125f;
            unsigned short qh = f2bf(q);
            long o = ((long)hh*S_LEN + gm)*64 + dh;
            p.qhi[o] = qh; p.qlo[o] = f2bf(q - bf2f(qh));
          } else if (which == 1){
            float kv = v + p.bias2[nn];
            unsigned short kh = f2bf(kv);
            long o = ((long)hh*S_LEN + gm)*64 + dh;
            p.khi[o] = kh; p.klo[o] = f2bf(kv - bf2f(kh));
          } else {
            float vv = v + p.bias3[nn];
            unsigned short vh = f2bf(vv);
            long o = ((long)hh*64 + dh)*S_LEN + gm;   // V^T: [h][d][s]
            p.vthi[o] = vh; p.vtlo[o] = f2bf(vv - bf2f(vh));
          }
        } else if (MODE == 1 || MODE == 4){
          long i = (long)gm*DMODEL + gn;
          p.outF[i] = v + p.bias[gn] + p.resid[i];
        }
      }
    }
  }
}

// ---------------- 256M x 128N MoE GEMM, 512 threads / 8 waves, PLANES=1 ----------------
// Shared 256-row A stage + 128-row B stage: halves B-panel re-fetch vs 128x128 blocks.
// MODE: 2=MOE1(gather A by pair_token)  3=MOE2(contiguous pair rows)
template<int MODE>
__global__ __launch_bounds__(512, 4) void gemm_big(GemmP p){
  const int tid  = threadIdx.x;
  const int lane = tid & 63;
  const int wave = tid >> 6;          // 0..7, 4x2 (wr x wc)
  const int quad = lane >> 4;
  const int ln   = lane & 15;
  const int wr = wave >> 1, wc = wave & 1;
  const int bn0 = blockIdx.x * 128;
  const int bm0 = blockIdx.y * 256;
  const int K = p.K;

  const int e = blockIdx.z;
  const int eoff = p.offs[e];
  const int Mloc = p.cnt[e];
  if (bm0 >= Mloc) return;
  const unsigned short* Bp = p.B + (long)e * FDIM * DMODEL;

  long aoff[2]; int koffA[2];
  #pragma unroll
  for (int j = 0; j < 2; j++){
    int c = tid + j*512;
    int row = c >> 2;
    koffA[j] = (c & 3) * 8;
    int r = bm0 + row; if (r >= Mloc) r = Mloc - 1;
    aoff[j] = (MODE == 2) ? (long)p.pair_token[eoff + r] * K : (long)(eoff + r) * K;
  }
  long boff; int koffB;
  {
    int row = tid >> 2;
    koffB = (tid & 3) * 8;
    boff = (long)(bn0 + row) * K;
  }

  __shared__ __align__(16) unsigned short As[256*32];
  __shared__ __align__(16) unsigned short Bs[128*32];

  f32x4 zero4 = {0.f, 0.f, 0.f, 0.f};
  f32x4 acc[4][4];
  #pragma unroll
  for (int i = 0; i < 4; i++)
    #pragma unroll
    for (int j = 0; j < 4; j++) acc[i][j] = zero4;

  for (int k0 = 0; k0 < K; k0 += 32){
    __syncthreads();
    #pragma unroll
    for (int j = 0; j < 2; j++){
      int c = tid + j*512;
      glds16(p.A + aoff[j] + k0 + koffA[j], &As[c*8]);
    }
    glds16(Bp + boff + k0 + koffB, &Bs[tid*8]);
    __syncthreads();
    bf16x8 af[4], bfr[4];
    #pragma unroll
    for (int mt = 0; mt < 4; mt++)
      af[mt] = *(const bf16x8*)&As[(wr*64 + mt*16 + ln)*32 + quad*8];
    #pragma unroll
    for (int nt = 0; nt < 4; nt++)
      bfr[nt] = *(const bf16x8*)&Bs[(wc*64 + nt*16 + ln)*32 + quad*8];
    #pragma unroll
    for (int mt = 0; mt < 4; mt++)
      #pragma unroll
      for (int nt = 0; nt < 4; nt++)
        acc[mt][nt] = mfma16(af[mt], bfr[nt], acc[mt][nt]);
  }

  #pragma unroll
  for (int mt = 0; mt < 4; mt++){
    #pragma unroll
    for (int nt = 0; nt < 4; nt++){
      #pragma unroll
      for (int r = 0; r < 4; r++){
        int gm = bm0 + wr*64 + mt*16 + quad*4 + r;
        int gn = bn0 + wc*64 + nt*16 + ln;
        if (gm < Mloc){
          float v = acc[mt][nt][r];
          if (MODE == 2){
            v = gelu_f(v + p.bias[(long)e*FDIM + gn]);
            p.outBF[(long)(eoff + gm)*FDIM + gn] = f2bf(v);
          } else {
            int pi = eoff + gm;
            p.outF[(long)pi*DMODEL + gn] = v + p.bias[(long)e*DMODEL + gn];
          }
        }
      }
    }
  }
}

// ---------------- MFMA sliding-window attention, split bf16 hi/lo (fp32-grade) ----------------
// grid (16 chunks, 12 heads, 4 strips of 64 q); block 256 (4 waves x 16-q sub-strip)
__global__ __launch_bounds__(256) void attn_mfma(
    const unsigned short* __restrict__ Qhi, const unsigned short* __restrict__ Qlo,
    const unsigned short* __restrict__ Khi, const unsigned short* __restrict__ Klo,
    const unsigned short* __restrict__ Vthi, const unsigned short* __restrict__ Vtlo,
    unsigned short* __restrict__ attn_hi, unsigned short* __restrict__ attn_lo){
  const int c = blockIdx.x, h = blockIdx.y, qb = blockIdx.z;
  const int tid = threadIdx.x;
  const int lane = tid & 63, w = tid >> 6;
  const int quad = lane >> 4, ln = lane & 15;
  const int q0 = c*256 + qb*64;
  const int qw = q0 + w*16;

  __shared__ __align__(16) unsigned short KsH[64*64], KsL[64*64];
  __shared__ __align__(16) unsigned short VsH[64*64], VsL[64*64];
  __shared__ __align__(16) unsigned short PsH[4][16*72], PsL[4][16*72];

  bf16x8 qf_h[2], qf_l[2];
  {
    long qrow = ((long)h*S_LEN + qw + ln)*64 + quad*8;
    qf_h[0] = *(const bf16x8*)(Qhi + qrow);
    qf_h[1] = *(const bf16x8*)(Qhi + qrow + 32);
    qf_l[0] = *(const bf16x8*)(Qlo + qrow);
    qf_l[1] = *(const bf16x8*)(Qlo + qrow + 32);
  }

  float m_s[4], l_s[4];
  f32x4 Oc[4];
  f32x4 z4 = {0.f,0.f,0.f,0.f};
  #pragma unroll
  for (int r = 0; r < 4; r++){ m_s[r] = -1e30f; l_s[r] = 0.f; }
  #pragma unroll
  for (int nt = 0; nt < 4; nt++) Oc[nt] = z4;

  const unsigned short* KhiB = Khi + (long)h*S_LEN*64;
  const unsigned short* KloB = Klo + (long)h*S_LEN*64;
  const unsigned short* VhiB = Vthi + (long)h*64*S_LEN;
  const unsigned short* VloB = Vtlo + (long)h*64*S_LEN;

  for (int kb = 0; kb < 12; kb++){
    const int kstart = c*256 - 256 + kb*64;
    if (kstart + 63 < 0 || kstart >= S_LEN) continue;
    if (kstart + 63 < q0 - 256 || kstart > q0 + 63 + 256) continue;
    __syncthreads();
    #pragma unroll
    for (int p2 = 0; p2 < 2; p2++){
      int idx = p2*256 + tid;
      int row = idx >> 3;
      int pc  = idx & 7;
      int lc  = pc ^ (row & 7);
      int ka = kstart + row;
      int kac = ka < 0 ? 0 : (ka > S_LEN-1 ? S_LEN-1 : ka);
      long gK = (long)kac*64 + lc*8;
      glds16(KhiB + gK, &KsH[idx*8]);
      glds16(KloB + gK, &KsL[idx*8]);
      int ks0 = kstart + lc*8;
      ks0 = ks0 < 0 ? 0 : (ks0 > S_LEN-8 ? S_LEN-8 : ks0);
      long gV = (long)row*S_LEN + ks0;
      glds16(VhiB + gV, &VsH[idx*8]);
      glds16(VloB + gV, &VsL[idx*8]);
    }
    __syncthreads();
    if (kstart + 63 < qw - 256 || kstart > qw + 15 + 256) continue;

    f32x4 Sc[4];
    #pragma unroll
    for (int nt = 0; nt < 4; nt++) Sc[nt] = z4;
    #pragma unroll
    for (int kc = 0; kc < 2; kc++){
      bf16x8 bh[4], bl[4];
      #pragma unroll
      for (int nt = 0; nt < 4; nt++){
        int row = nt*16 + ln;
        int o = row*64 + (((kc*4 + quad) ^ (row & 7))*8);
        bh[nt] = *(const bf16x8*)&KsH[o];
        bl[nt] = *(const bf16x8*)&KsL[o];
      }
      #pragma unroll
      for (int nt = 0; nt < 4; nt++){
        Sc[nt] = mfma16(qf_h[kc], bh[nt], Sc[nt]);
        Sc[nt] = mfma16(qf_h[kc], bl[nt], Sc[nt]);
        Sc[nt] = mfma16(qf_l[kc], bh[nt], Sc[nt]);
      }
    }
    bool interior = (kstart >= qw - 241) && (kstart <= qw + 193) &&
                    (kstart >= 0) && (kstart + 63 <= S_LEN - 1);
    if (!interior){
      #pragma unroll
      for (int nt = 0; nt < 4; nt++){
        int ka = kstart + nt*16 + ln;
        #pragma unroll
        for (int r = 0; r < 4; r++){
          int qa = qw + quad*4 + r;
          bool v = (ka >= 0) && (ka < S_LEN) && (ka >= qa - 256) && (ka <= qa + 256);
          if (!v) Sc[nt][r] = -3.0e38f;
        }
      }
    }
    float bm[4];
    #pragma unroll
    for (int r = 0; r < 4; r++)
      bm[r] = fmaxf(fmaxf(Sc[0][r], Sc[1][r]), fmaxf(Sc[2][r], Sc[3][r]));
    #pragma unroll
    for (int off = 1; off < 16; off <<= 1)
      #pragma unroll
      for (int r = 0; r < 4; r++) bm[r] = fmaxf(bm[r], __shfl_xor(bm[r], off));
    float al[4];
    #pragma unroll
    for (int r = 0; r < 4; r++){
      float mnew = fmaxf(m_s[r], bm[r]);
      al[r] = __expf(m_s[r] - mnew);
      m_s[r] = mnew;
    }
    float psum[4] = {0.f,0.f,0.f,0.f};
    #pragma unroll
    for (int nt = 0; nt < 4; nt++){
      #pragma unroll
      for (int r = 0; r < 4; r++){
        float pv = __expf(Sc[nt][r] - m_s[r]);
        psum[r] += pv;
        unsigned short ph = f2bf(pv);
        int o = (quad*4 + r)*72 + nt*16 + ln;
        PsH[w][o] = ph;
        PsL[w][o] = f2bf(pv - bf2f(ph));
      }
    }
    #pragma unroll
    for (int off = 1; off < 16; off <<= 1)
      #pragma unroll
      for (int r = 0; r < 4; r++) psum[r] += __shfl_xor(psum[r], off);
    #pragma unroll
    for (int r = 0; r < 4; r++) l_s[r] = l_s[r]*al[r] + psum[r];
    #pragma unroll
    for (int nt = 0; nt < 4; nt++)
      #pragma unroll
      for (int r = 0; r < 4; r++) Oc[nt][r] *= al[r];
    asm volatile("s_waitcnt lgkmcnt(0)" ::: "memory");
    #pragma unroll
    for (int kc = 0; kc < 2; kc++){
      bf16x8 ph = *(const bf16x8*)&PsH[w][ln*72 + kc*32 + quad*8];
      bf16x8 pl = *(const bf16x8*)&PsL[w][ln*72 + kc*32 + quad*8];
      #pragma unroll
      for (int nt = 0; nt < 4; nt++){
        int row = nt*16 + ln;
        int o = row*64 + (((kc*4 + quad) ^ (row & 7))*8);
        bf16x8 vh = *(const bf16x8*)&VsH[o];
        bf16x8 vl = *(const bf16x8*)&VsL[o];
        Oc[nt] = mfma16(ph, vh, Oc[nt]);
        Oc[nt] = mfma16(ph, vl, Oc[nt]);
        Oc[nt] = mfma16(pl, vh, Oc[nt]);
      }
    }
  }
  float inv[4];
  #pragma unroll
  for (int r = 0; r < 4; r++) inv[r] = 1.f / l_s[r];
  #pragma unroll
  for (int nt = 0; nt < 4; nt++){
    #pragma unroll
    for (int r = 0; r < 4; r++){
      int qa = qw + quad*4 + r;
      long o = (long)qa*DMODEL + h*64 + nt*16 + ln;
      float ov = Oc[nt][r] * inv[r];
      unsigned short oh = f2bf(ov);
      attn_hi[o] = oh;
      attn_lo[o] = f2bf(ov - bf2f(oh));
    }
  }
}

// ---------------- LayerNorm (fp32), optional bf16 copy ----------------
__global__ __launch_bounds__(256) void ln_kernel(const float* __restrict__ x,
    const float* __restrict__ g, const float* __restrict__ b,
    float* __restrict__ outF, unsigned short* __restrict__ outBF){
  int s = blockIdx.x;
  const float* row = x + (long)s*DMODEL;
  int t = threadIdx.x;
  float v0 = row[t], v1 = row[t+256], v2 = row[t+512];
  float sum = v0+v1+v2;
  float sq  = v0*v0 + v1*v1 + v2*v2;
  for (int o = 32; o > 0; o >>= 1){ sum += __shfl_xor(sum, o); sq += __shfl_xor(sq, o); }
  __shared__ float s1[4], s2[4];
  int wv = t >> 6;
  if ((t & 63) == 0){ s1[wv] = sum; s2[wv] = sq; }
  __syncthreads();
  sum = s1[0]+s1[1]+s1[2]+s1[3];
  sq  = s2[0]+s2[1]+s2[2]+s2[3];
  float mean = sum * (1.0f/DMODEL);
  float var  = sq  * (1.0f/DMODEL) - mean*mean;
  float inv = rsqrtf(var + 1e-5f);
  float* orow = outF + (long)s*DMODEL;
  unsigned short* brow = outBF ? outBF + (long)s*DMODEL : (unsigned short*)0;
  #pragma unroll
  for (int j = 0; j < 3; j++){
    int d = t + j*256;
    float y = (row[d] - mean) * inv * g[d] + b[d];
    orow[d] = y;
    if (brow) brow[d] = f2bf(y);
  }
}

// ---------------- gate: fp32 logits, top-2, softmax, routing records ----------------
__global__ __launch_bounds__(64) void gate_kernel(const float* __restrict__ x,
    const float* __restrict__ gw, const float* __restrict__ gb,
    float* __restrict__ gate_out, int* __restrict__ tok_e,
    float* __restrict__ tok_w, int* __restrict__ cnt){
  int s = blockIdx.x;
  int lane = threadIdx.x;
  float acc[NEXP];
  #pragma unroll
  for (int e = 0; e < NEXP; e++) acc[e] = 0.f;
  const float* xr = x + (long)s*DMODEL;
  for (int d = lane; d < DMODEL; d += 64){
    float xv = xr[d];
    const float* wr = gw + (long)d*NEXP;
    #pragma unroll
    for (int e = 0; e < NEXP; e++) acc[e] += xv * wr[e];
  }
  #pragma unroll
  for (int e = 0; e < NEXP; e++){
    float v = acc[e];
    for (int o = 32; o > 0; o >>= 1) v += __shfl_xor(v, o);
    acc[e] = v;
  }
  if (lane == 0){
    #pragma unroll
    for (int e = 0; e < NEXP; e++) acc[e] += gb[e];
    int i0 = 0;
    for (int e = 1; e < NEXP; e++) if (acc[e] > acc[i0]) i0 = e;
    int i1 = -1;
    for (int e = 0; e < NEXP; e++) if (e != i0 && (i1 < 0 || acc[e] > acc[i1])) i1 = e;
    float e1 = expf(acc[i1] - acc[i0]);
    float inv = 1.f / (1.f + e1);
    float w0 = inv, w1 = e1 * inv;
    float* go = gate_out + (long)s*NEXP;
    #pragma unroll
    for (int e = 0; e < NEXP; e++) go[e] = 0.f;
    go[i0] = w0; go[i1] = w1;
    tok_e[s*2] = i0; tok_e[s*2+1] = i1;
    tok_w[s*2] = w0; tok_w[s*2+1] = w1;
    atomicAdd(&cnt[i0], 1);
    atomicAdd(&cnt[i1], 1);
  }
}

__global__ void scan_kernel(const int* __restrict__ cnt, int* __restrict__ offs){
  if (threadIdx.x == 0 && blockIdx.x == 0){
    int s = 0;
    for (int e = 0; e < NEXP; e++){ offs[e] = s; s += cnt[e]; }
  }
}

__global__ __launch_bounds__(256) void scatter_kernel(const int* __restrict__ tok_e,
    const float* __restrict__ tok_w, const int* __restrict__ offs, int* __restrict__ fill,
    int* __restrict__ pair_token, float* __restrict__ pair_w, int* __restrict__ tok_pi){
  int t = blockIdx.x*256 + threadIdx.x;
  if (t >= S_LEN) return;
  #pragma unroll
  for (int sl = 0; sl < 2; sl++){
    int e = tok_e[t*2+sl];
    int pos = atomicAdd(&fill[e], 1);
    int pi = offs[e] + pos;
    pair_token[pi] = t;
    pair_w[pi] = tok_w[t*2+sl];
    tok_pi[t*2+sl] = pi;
  }
}

// ---------------- combine: moe[t] = w0*P[p0] + w1*P[p1] -> bf16 ----------------
__global__ __launch_bounds__(256) void combine_kernel(const float* __restrict__ Pbuf,
    const int* __restrict__ tok_pi, const float* __restrict__ tok_w,
    unsigned short* __restrict__ moe_bf){
  int t = blockIdx.x;
  int d = threadIdx.x;
  float w0 = tok_w[t*2], w1 = tok_w[t*2+1];
  long p0 = (long)tok_pi[t*2]   * DMODEL;
  long p1 = (long)tok_pi[t*2+1] * DMODEL;
  unsigned short* orow = moe_bf + (long)t*DMODEL;
  #pragma unroll
  for (int j = 0; j < 3; j++){
    int dd = d + j*256;
    orow[dd] = f2bf(w0*Pbuf[p0+dd] + w1*Pbuf[p1+dd]);
  }
}

// ---------------- host launch ----------------
extern "C" void kernel_launch(void* const* d_in, const int* in_sizes, int n_in,
                              void* d_out, int out_size, void* d_ws, size_t ws_size,
                              hipStream_t stream){
  (void)in_sizes; (void)n_in; (void)out_size; (void)ws_size;
  const float* hidden = (const float*)d_in[0];
  const float* Wq  = (const float*)d_in[1];
  const float* bq  = (const float*)d_in[2];
  const float* Wk  = (const float*)d_in[3];
  const float* bk  = (const float*)d_in[4];
  const float* Wv  = (const float*)d_in[5];
  const float* bv  = (const float*)d_in[6];
  const float* Wo  = (const float*)d_in[7];
  const float* bo  = (const float*)d_in[8];
  const float* ln1g = (const float*)d_in[9];
  const float* ln1b = (const float*)d_in[10];
  const float* gateW = (const float*)d_in[11];
  const float* gateB = (const float*)d_in[12];
  const float* W1e = (const float*)d_in[13];
  const float* b1e = (const float*)d_in[14];
  const float* W2e = (const float*)d_in[15];
  const float* b2e = (const float*)d_in[16];
  const float* Wd  = (const float*)d_in[17];
  const float* bd  = (const float*)d_in[18];
  const float* ln2g = (const float*)d_in[19];
  const float* ln2b = (const float*)d_in[20];

  float* outL = (float*)d_out;
  float* outG = outL + (size_t)S_LEN*DMODEL;

  const size_t SD = (size_t)S_LEN*DMODEL;
  char* base = (char*)d_ws;
  size_t off = 0;
  auto alloc = [&](size_t bytes)->void*{
    void* r = base + off;
    off = (off + bytes + 255) & ~(size_t)255;
    return r;
  };
  unsigned short* x_hi    = (unsigned short*)alloc(SD*2);
  unsigned short* x_lo    = (unsigned short*)alloc(SD*2);
  unsigned short* wqkv_hi = (unsigned short*)alloc((size_t)2304*768*2);
  unsigned short* wqkv_lo = (unsigned short*)alloc((size_t)2304*768*2);
  unsigned short* wo_hi   = (unsigned short*)alloc((size_t)768*768*2);
  unsigned short* wo_lo   = (unsigned short*)alloc((size_t)768*768*2);
  unsigned short* wd_bf   = (unsigned short*)alloc((size_t)768*768*2);
  unsigned short* w1_bf   = (unsigned short*)alloc((size_t)NEXP*FDIM*DMODEL*2);
  unsigned short* w2_bf   = (unsigned short*)alloc((size_t)NEXP*FDIM*DMODEL*2);
  unsigned short* q_hi  = (unsigned short*)alloc(SD*2);
  unsigned short* q_lo  = (unsigned short*)alloc(SD*2);
  unsigned short* k_hi  = (unsigned short*)alloc(SD*2);
  unsigned short* k_lo  = (unsigned short*)alloc(SD*2);
  unsigned short* vt_hi = (unsigned short*)alloc(SD*2);
  unsigned short* vt_lo = (unsigned short*)alloc(SD*2);
  unsigned short* attn_hi = (unsigned short*)alloc(SD*2);
  unsigned short* attn_lo = (unsigned short*)alloc(SD*2);
  float* preLN1    = (float*)alloc(SD*4);
  float* attnout_f = (float*)alloc(SD*4);
  unsigned short* attnout_bf = (unsigned short*)alloc(SD*2);
  int*   tok_e = (int*)alloc(2*S_LEN*4);
  float* tok_w = (float*)alloc(2*S_LEN*4);
  int*   tok_pi = (int*)alloc(2*S_LEN*4);
  int*   cnt   = (int*)alloc(32*4);      // cnt[0:8], fill at +8
  int*   fill  = cnt + 8;
  int*   offs  = (int*)alloc(32*4);
  int*   pair_token = (int*)alloc(NPAIR*4);
  float* pair_w     = (float*)alloc(NPAIR*4);
  unsigned short* Hbuf = (unsigned short*)alloc((size_t)NPAIR*FDIM*2);
  // aliases: q/k/vt planes (6*SD*2 = 37.7MB contiguous) dead after attn_mfma.
  float* Pbuf = (float*)q_hi;
  unsigned short* moe_bf = (unsigned short*)((char*)q_hi + (size_t)NPAIR*DMODEL*4);
  float* preLN2 = preLN1;

  // 1. split hidden -> bf16 hi/lo
  split_kernel<<<dim3((unsigned)(SD/256)), dim3(256), 0, stream>>>(hidden, x_hi, x_lo, (int)SD);
  // 2. weight transposes/converts
  transp_kernel<1><<<dim3(24,24,1), dim3(32,8), 0, stream>>>(Wq, wqkv_hi,           wqkv_lo,           DMODEL, DMODEL, 0, 0);
  transp_kernel<1><<<dim3(24,24,1), dim3(32,8), 0, stream>>>(Wk, wqkv_hi+768*768,   wqkv_lo+768*768,   DMODEL, DMODEL, 0, 0);
  transp_kernel<1><<<dim3(24,24,1), dim3(32,8), 0, stream>>>(Wv, wqkv_hi+2*768*768, wqkv_lo+2*768*768, DMODEL, DMODEL, 0, 0);
  transp_kernel<1><<<dim3(24,24,1), dim3(32,8), 0, stream>>>(Wo, wo_hi, wo_lo, DMODEL, DMODEL, 0, 0);
  transp_kernel<0><<<dim3(24,24,1), dim3(32,8), 0, stream>>>(Wd, wd_bf, nullptr, DMODEL, DMODEL, 0, 0);
  transp_kernel<0><<<dim3(96,24,NEXP), dim3(32,8), 0, stream>>>(W1e, w1_bf, nullptr, DMODEL, FDIM, (long)DMODEL*FDIM, (long)DMODEL*FDIM);
  transp_kernel<0><<<dim3(24,96,NEXP), dim3(32,8), 0, stream>>>(W2e, w2_bf, nullptr, FDIM, DMODEL, (long)DMODEL*FDIM, (long)DMODEL*FDIM);

  // 3. QKV projection -> Q,K hi/lo [h][s][64]; V hi/lo transposed [h][d][s]
  GemmP pq = {};
  pq.A = x_hi; pq.Alo = x_lo; pq.B = wqkv_hi; pq.Blo = wqkv_lo;
  pq.M = S_LEN; pq.N = 2304; pq.K = DMODEL;
  pq.bias = bq; pq.bias2 = bk; pq.bias3 = bv;
  pq.qhi = q_hi; pq.qlo = q_lo; pq.khi = k_hi; pq.klo = k_lo; pq.vthi = vt_hi; pq.vtlo = vt_lo;
  gemm_bt<0,2><<<dim3(18,32,1), dim3(256), 0, stream>>>(pq);

  // 4. MFMA attention -> attn hi/lo bf16 planes
  attn_mfma<<<dim3(16,NHEADS,4), dim3(256), 0, stream>>>(q_hi, q_lo, k_hi, k_lo, vt_hi, vt_lo, attn_hi, attn_lo);

  // 5. Wo projection + bias + residual -> preLN1 (fp32)
  GemmP pw = {};
  pw.A = attn_hi; pw.Alo = attn_lo; pw.B = wo_hi; pw.Blo = wo_lo;
  pw.M = S_LEN; pw.N = DMODEL; pw.K = DMODEL;
  pw.bias = bo; pw.resid = hidden; pw.outF = preLN1;
  gemm_bt<1,2><<<dim3(6,32,1), dim3(256), 0, stream>>>(pw);

  // 6. LN1 -> attnout (fp32 + bf16)
  ln_kernel<<<dim3(S_LEN), dim3(256), 0, stream>>>(preLN1, ln1g, ln1b, attnout_f, attnout_bf);

  // 7. zero routing counters
  hipMemsetAsync(cnt, 0, 64, stream);

  // 8. gate + routing
  gate_kernel<<<dim3(S_LEN), dim3(64), 0, stream>>>(attnout_f, gateW, gateB, outG, tok_e, tok_w, cnt);
  scan_kernel<<<dim3(1), dim3(64), 0, stream>>>(cnt, offs);
  scatter_kernel<<<dim3(S_LEN/256), dim3(256), 0, stream>>>(tok_e, tok_w, offs, fill, pair_token, pair_w, tok_pi);

  // 9. MoE expert GEMMs (top-2 sparse), 256M x 128N shared-stage blocks
  GemmP p1 = {};
  p1.A = attnout_bf; p1.B = w1_bf; p1.M = S_LEN; p1.N = FDIM; p1.K = DMODEL;
  p1.bias = b1e; p1.outBF = Hbuf;
  p1.pair_token = pair_token; p1.cnt = cnt; p1.offs = offs;
  gemm_big<2><<<dim3(24,16,NEXP), dim3(512), 0, stream>>>(p1);

  GemmP p2 = {};
  p2.A = Hbuf; p2.B = w2_bf; p2.M = S_LEN; p2.N = DMODEL; p2.K = FDIM;
  p2.bias = b2e; p2.outF = Pbuf;
  p2.pair_token = pair_token; p2.pair_w = pair_w; p2.cnt = cnt; p2.offs = offs;
  gemm_big<3><<<dim3(6,16,NEXP), dim3(512), 0, stream>>>(p2);

  // 10. combine pairs -> moe bf16; Wd + bias + residual(attention_output) -> preLN2
  combine_kernel<<<dim3(S_LEN), dim3(256), 0, stream>>>(Pbuf, tok_pi, tok_w, moe_bf);
  GemmP pd = {};
  pd.A = moe_bf; pd.B = wd_bf; pd.M = S_LEN; pd.N = DMODEL; pd.K = DMODEL;
  pd.bias = bd; pd.resid = attnout_f; pd.outF = preLN2;
  gemm_bt<4,1><<<dim3(6,32,1), dim3(256), 0, stream>>>(pd);

  // 11. LN2 -> layer_output
  ln_kernel<<<dim3(S_LEN), dim3(256), 0, stream>>>(preLN2, ln2g, ln2b, outL, nullptr);
}